// Round 6
// baseline (1075.154 us; speedup 1.0000x reference)
//
#include <hip/hip_runtime.h>
#include <math.h>

// ---------------- dims ----------------
#define BB 64
#define H1 116
#define W1 212
#define C1c 10
#define OH1 112
#define OW1 208
#define PH1 56
#define PW1 104
#define C2c 20
#define OH2 52
#define OW2 100
#define PH2 26
#define PW2 50
#define FLAT 26000
#define HID 512
#define NCLS 10
#define EPSV 1e-5
#define NB1 1456
#define NB2 163          // conv2 blocks per channel-group (ceil(41600/256))
#define COG 2            // conv2 output channels per thread

// ============================================================
// init: bias-init FC accumulators
// ============================================================
__global__ __launch_bounds__(256) void k_init(
                       float* fc1r, float* fc1i, float* fc2r, float* fc2i,
                       const float* __restrict__ f1br, const float* __restrict__ f1bi,
                       const float* __restrict__ f2br, const float* __restrict__ f2bi) {
    int idx = blockIdx.x * 256 + threadIdx.x;
    if (idx < BB * HID) {
        int n = idx % HID;
        fc1r[idx] = f1br[n]; fc1i[idx] = f1bi[n];
        fc2r[idx] = f2br[n]; fc2i[idx] = f2bi[n];
    }
}

// ============================================================
// conv1 + stats partials (no store; conv1 recomputed in apply pass)
// grid (1456, 10), block 256.  f32 moment reduce, f64 partial write.
// ============================================================
__global__ __launch_bounds__(256) void k_conv1_stats(
                              const float* __restrict__ xr, const float* __restrict__ xi,
                              const float* __restrict__ w1r, const float* __restrict__ w1i,
                              const float* __restrict__ b1r, const float* __restrict__ b1i,
                              double* __restrict__ part) {
    __shared__ float swr[25], swi[25];
    __shared__ float red[4][5];
    int tid = threadIdx.x;
    int c = blockIdx.y;
    if (tid < 25) { swr[tid] = w1r[c * 25 + tid]; swi[tid] = w1i[c * 25 + tid]; }
    __syncthreads();
    int idx = blockIdx.x * 256 + tid;
    int wg = idx % 52;
    int h  = (idx / 52) % OH1;
    int b  = idx / (52 * OH1);
    int w0 = wg * 4;
    float br = b1r[c], bi = b1i[c];
    float yr[4], yi[4];
#pragma unroll
    for (int j = 0; j < 4; j++) { yr[j] = br; yi[j] = bi; }
    const float* xrb = xr + b * (H1 * W1);
    const float* xib = xi + b * (H1 * W1);
#pragma unroll
    for (int kh = 0; kh < 5; kh++) {
        float ar[8], ai[8];
        const float* pr = xrb + (h + kh) * W1 + w0;
        const float* pi = xib + (h + kh) * W1 + w0;
        *(float4*)&ar[0] = *(const float4*)pr;
        *(float4*)&ar[4] = *(const float4*)(pr + 4);
        *(float4*)&ai[0] = *(const float4*)pi;
        *(float4*)&ai[4] = *(const float4*)(pi + 4);
#pragma unroll
        for (int kw = 0; kw < 5; kw++) {
            float wrv = swr[kh * 5 + kw], wiv = swi[kh * 5 + kw];
#pragma unroll
            for (int j = 0; j < 4; j++) {
                float vr = ar[kw + j], vi = ai[kw + j];
                yr[j] += vr * wrv - vi * wiv;
                yi[j] += vr * wiv + vi * wrv;
            }
        }
    }
    float v[5] = {0.f, 0.f, 0.f, 0.f, 0.f};
#pragma unroll
    for (int j = 0; j < 4; j++) {
        float r = yr[j], i = yi[j];
        v[0] += r; v[1] += i; v[2] += r * r; v[3] += i * i; v[4] += r * i;
    }
#pragma unroll
    for (int m = 32; m >= 1; m >>= 1) {
#pragma unroll
        for (int q = 0; q < 5; q++) v[q] += __shfl_xor(v[q], m, 64);
    }
    if ((tid & 63) == 0) {
#pragma unroll
        for (int q = 0; q < 5; q++) red[tid >> 6][q] = v[q];
    }
    __syncthreads();
    if (tid == 0) {
#pragma unroll
        for (int q = 0; q < 5; q++)
            part[(c * 5 + q) * NB1 + blockIdx.x] =
                (double)red[0][q] + (double)red[1][q] + (double)red[2][q] + (double)red[3][q];
    }
}

// ============================================================
// reduce per-block partials -> sums[c*5+q]
// ============================================================
__global__ __launch_bounds__(320) void k_part_reduce(
                              const double* __restrict__ part, int NB,
                              double* __restrict__ sums) {
    int c = blockIdx.x;
    int q = threadIdx.x >> 6;
    int lane = threadIdx.x & 63;
    double s = 0.0;
    for (int b = lane; b < NB; b += 64) s += part[(c * 5 + q) * NB + b];
#pragma unroll
    for (int m = 32; m >= 1; m >>= 1) s += __shfl_xor(s, m, 64);
    if (lane == 0) sums[c * 5 + q] = s;
}

// ============================================================
// BN coefficients from double sums (conv layers)
// ============================================================
__global__ __launch_bounds__(64) void k_bn_coef(
                          const double* __restrict__ sums, int C, double invN,
                          const float* __restrict__ grr, const float* __restrict__ gri,
                          const float* __restrict__ gii,
                          const float* __restrict__ ber, const float* __restrict__ bei,
                          float* __restrict__ coef) {
    int c = threadIdx.x;
    if (c >= C) return;
    double sr = sums[c * 5 + 0], si = sums[c * 5 + 1];
    double srr = sums[c * 5 + 2], sii = sums[c * 5 + 3], sri = sums[c * 5 + 4];
    double mr = sr * invN, mi = si * invN;
    double Vrr = srr * invN - mr * mr + EPSV;
    double Vii = sii * invN - mi * mi + EPSV;
    double Vri = sri * invN - mr * mi;
    double s = sqrt(Vrr * Vii - Vri * Vri);
    double t = sqrt(Vrr + Vii + 2.0 * s);
    double inv = 1.0 / (s * t);
    double Rrr = (Vii + s) * inv, Rii = (Vrr + s) * inv, Rri = -Vri * inv;
    double Grr = grr[c], Gri = gri[c], Gii = gii[c];
    double Arr = Grr * Rrr + Gri * Rri, Ari = Grr * Rri + Gri * Rii;
    double Air = Gri * Rrr + Gii * Rri, Aii = Gri * Rri + Gii * Rii;
    coef[c * 6 + 0] = (float)Arr;
    coef[c * 6 + 1] = (float)Ari;
    coef[c * 6 + 2] = (float)Air;
    coef[c * 6 + 3] = (float)Aii;
    coef[c * 6 + 4] = (float)((double)ber[c] - (Arr * mr + Ari * mi));
    coef[c * 6 + 5] = (float)((double)bei[c] - (Air * mr + Aii * mi));
}

// ============================================================
// conv1 recompute + BN affine + relu + mag-pool -> P1 [b][c][56][104]
// grid (728, 10)
// ============================================================
__global__ __launch_bounds__(256) void k_conv1_apply_pool(
                                   const float* __restrict__ xr, const float* __restrict__ xi,
                                   const float* __restrict__ w1r, const float* __restrict__ w1i,
                                   const float* __restrict__ b1r, const float* __restrict__ b1i,
                                   const float* __restrict__ coef,
                                   float* __restrict__ P1r, float* __restrict__ P1i) {
    __shared__ float swr[25], swi[25];
    int tid = threadIdx.x;
    int c = blockIdx.y;
    if (tid < 25) { swr[tid] = w1r[c * 25 + tid]; swi[tid] = w1i[c * 25 + tid]; }
    __syncthreads();
    int idx = blockIdx.x * 256 + tid;
    int pwg = idx % 52;
    int ph  = (idx / 52) % PH1;
    int b   = idx / (52 * PH1);
    int h0 = 2 * ph, w0 = 4 * pwg;
    float br = b1r[c], bi = b1i[c];
    float yr[2][4], yi[2][4];
#pragma unroll
    for (int oi = 0; oi < 2; oi++)
#pragma unroll
        for (int j = 0; j < 4; j++) { yr[oi][j] = br; yi[oi][j] = bi; }
    const float* xrb = xr + b * (H1 * W1);
    const float* xib = xi + b * (H1 * W1);
#pragma unroll
    for (int r = 0; r < 6; r++) {
        float ar[8], ai[8];
        const float* pr = xrb + (h0 + r) * W1 + w0;
        const float* pi = xib + (h0 + r) * W1 + w0;
        *(float4*)&ar[0] = *(const float4*)pr;
        *(float4*)&ar[4] = *(const float4*)(pr + 4);
        *(float4*)&ai[0] = *(const float4*)pi;
        *(float4*)&ai[4] = *(const float4*)(pi + 4);
#pragma unroll
        for (int oi = 0; oi < 2; oi++) {
            int kh = r - oi;
            if (kh >= 0 && kh < 5) {
#pragma unroll
                for (int kw = 0; kw < 5; kw++) {
                    float wrv = swr[kh * 5 + kw], wiv = swi[kh * 5 + kw];
#pragma unroll
                    for (int j = 0; j < 4; j++) {
                        float vr = ar[kw + j], vi = ai[kw + j];
                        yr[oi][j] += vr * wrv - vi * wiv;
                        yi[oi][j] += vr * wiv + vi * wrv;
                    }
                }
            }
        }
    }
    float Arr = coef[c * 6 + 0], Ari = coef[c * 6 + 1];
    float Air = coef[c * 6 + 2], Aii = coef[c * 6 + 3];
    float oR = coef[c * 6 + 4], oI = coef[c * 6 + 5];
    float bm0 = -1.f, br0 = 0.f, bi0 = 0.f;
    float bm1 = -1.f, br1 = 0.f, bi1 = 0.f;
#pragma unroll
    for (int oi = 0; oi < 2; oi++) {
#pragma unroll
        for (int j = 0; j < 4; j++) {
            float rr = fmaxf(Arr * yr[oi][j] + Ari * yi[oi][j] + oR, 0.f);
            float ii = fmaxf(Air * yr[oi][j] + Aii * yi[oi][j] + oI, 0.f);
            float m = rr * rr + ii * ii;
            if (j < 2) { if (m > bm0) { bm0 = m; br0 = rr; bi0 = ii; } }
            else       { if (m > bm1) { bm1 = m; br1 = rr; bi1 = ii; } }
        }
    }
    int pbase = ((b * C1c + c) * PH1 + ph) * PW1 + 2 * pwg;
    *(float2*)&P1r[pbase] = make_float2(br0, br1);
    *(float2*)&P1i[pbase] = make_float2(bi0, bi1);
}

// ============================================================
// conv2: P1 -> buf2 [b][c][52][100] (stored) + stats partials
// grid (163, 10): COG=2 channels x 2 output rows x 4 pixels per thread.
// Weights read via wave-uniform global indices -> scalar (s_load) path,
// no LDS staging. 6 shared input rows per 2 output rows.
// ============================================================
__global__ __launch_bounds__(256) void k_conv2_stats(
                              const float* __restrict__ P1r, const float* __restrict__ P1i,
                              const float* __restrict__ w2r, const float* __restrict__ w2i,
                              const float* __restrict__ b2r, const float* __restrict__ b2i,
                              float* __restrict__ buf2r, float* __restrict__ buf2i,
                              double* __restrict__ part) {
    __shared__ float red[4][5];
    int tid = threadIdx.x;
    int cg = blockIdx.y;                     // couts cg*2, cg*2+1
    int idx = blockIdx.x * 256 + tid;
    bool valid = idx < (BB * PH2 * 25);      // 64*26*25 = 41600
    int idc = valid ? idx : 0;
    int wg = idc % 25;
    int hp = (idc / 25) % PH2;               // output-row pair
    int b  = idc / (25 * PH2);
    int h0 = 2 * hp, w0 = 4 * wg;
    const float* wrbase = w2r + cg * COG * 250;
    const float* wibase = w2i + cg * COG * 250;
    float yr[COG][2][4], yi[COG][2][4];
#pragma unroll
    for (int g = 0; g < COG; g++) {
        float brv = b2r[cg * COG + g], biv = b2i[cg * COG + g];
#pragma unroll
        for (int oh = 0; oh < 2; oh++)
#pragma unroll
            for (int j = 0; j < 4; j++) { yr[g][oh][j] = brv; yi[g][oh][j] = biv; }
    }
    for (int cin = 0; cin < C1c; cin++) {
        const float* pr = P1r + ((b * C1c + cin) * PH1 + h0) * PW1 + w0;
        const float* pi = P1i + ((b * C1c + cin) * PH1 + h0) * PW1 + w0;
#pragma unroll
        for (int r = 0; r < 6; r++) {
            float ar[8], ai[8];
            *(float4*)&ar[0] = *(const float4*)(pr + r * PW1);
            *(float4*)&ar[4] = *(const float4*)(pr + r * PW1 + 4);
            *(float4*)&ai[0] = *(const float4*)(pi + r * PW1);
            *(float4*)&ai[4] = *(const float4*)(pi + r * PW1 + 4);
#pragma unroll
            for (int oh = 0; oh < 2; oh++) {
                int kh = r - oh;
                if (kh >= 0 && kh < 5) {
#pragma unroll
                    for (int g = 0; g < COG; g++) {
                        int wb = g * 250 + cin * 25 + kh * 5;
#pragma unroll
                        for (int kw = 0; kw < 5; kw++) {
                            float wrv = wrbase[wb + kw];   // wave-uniform -> SGPR
                            float wiv = wibase[wb + kw];
#pragma unroll
                            for (int j = 0; j < 4; j++) {
                                float vr = ar[kw + j], vi = ai[kw + j];
                                yr[g][oh][j] += vr * wrv - vi * wiv;
                                yi[g][oh][j] += vr * wiv + vi * wrv;
                            }
                        }
                    }
                }
            }
        }
    }
    if (valid) {
#pragma unroll
        for (int g = 0; g < COG; g++) {
#pragma unroll
            for (int oh = 0; oh < 2; oh++) {
                int ob = ((b * C2c + cg * COG + g) * OH2 + h0 + oh) * OW2 + w0;
                *(float4*)&buf2r[ob] = make_float4(yr[g][oh][0], yr[g][oh][1], yr[g][oh][2], yr[g][oh][3]);
                *(float4*)&buf2i[ob] = make_float4(yi[g][oh][0], yi[g][oh][1], yi[g][oh][2], yi[g][oh][3]);
            }
        }
    } else {
        // zero so stats sums are unaffected
#pragma unroll
        for (int g = 0; g < COG; g++)
#pragma unroll
            for (int oh = 0; oh < 2; oh++)
#pragma unroll
                for (int j = 0; j < 4; j++) { yr[g][oh][j] = 0.f; yi[g][oh][j] = 0.f; }
    }
    // stats: f32 per-wave reduce, f64 only at partial write
    for (int g = 0; g < COG; g++) {
        float v[5] = {0.f, 0.f, 0.f, 0.f, 0.f};
#pragma unroll
        for (int oh = 0; oh < 2; oh++)
#pragma unroll
            for (int j = 0; j < 4; j++) {
                float r = yr[g][oh][j], i = yi[g][oh][j];
                v[0] += r; v[1] += i; v[2] += r * r; v[3] += i * i; v[4] += r * i;
            }
#pragma unroll
        for (int m = 32; m >= 1; m >>= 1) {
#pragma unroll
            for (int q = 0; q < 5; q++) v[q] += __shfl_xor(v[q], m, 64);
        }
        if ((tid & 63) == 0) {
#pragma unroll
            for (int q = 0; q < 5; q++) red[tid >> 6][q] = v[q];
        }
        __syncthreads();
        if (tid == 0) {
            int c = cg * COG + g;
#pragma unroll
            for (int q = 0; q < 5; q++)
                part[(c * 5 + q) * NB2 + blockIdx.x] =
                    (double)red[0][q] + (double)red[1][q] + (double)red[2][q] + (double)red[3][q];
        }
        __syncthreads();
    }
}

// ============================================================
// BN2 affine + relu + mag-pool, write transposed P2T [k=26000][b=64]
// ============================================================
__global__ __launch_bounds__(256) void k_bn2_pool(
                           const float* __restrict__ buf2r, const float* __restrict__ buf2i,
                           const float* __restrict__ coef,
                           float* __restrict__ P2Tr, float* __restrict__ P2Ti) {
    int idx = blockIdx.x * 256 + threadIdx.x;
    int pw = idx % PW2;
    int ph = (idx / PW2) % PH2;
    int c  = (idx / (PW2 * PH2)) % C2c;
    int b  = idx / (PW2 * PH2 * C2c);
    float Arr = coef[c * 6 + 0], Ari = coef[c * 6 + 1];
    float Air = coef[c * 6 + 2], Aii = coef[c * 6 + 3];
    float oR = coef[c * 6 + 4], oI = coef[c * 6 + 5];
    int ib = ((b * C2c + c) * OH2 + 2 * ph) * OW2 + 2 * pw;
    float rv[4], iv[4];
    rv[0] = buf2r[ib];           iv[0] = buf2i[ib];
    rv[1] = buf2r[ib + 1];       iv[1] = buf2i[ib + 1];
    rv[2] = buf2r[ib + OW2];     iv[2] = buf2i[ib + OW2];
    rv[3] = buf2r[ib + OW2 + 1]; iv[3] = buf2i[ib + OW2 + 1];
    float bm = -1.f, brv = 0.f, biv = 0.f;
#pragma unroll
    for (int q = 0; q < 4; q++) {
        float rr = fmaxf(Arr * rv[q] + Ari * iv[q] + oR, 0.f);
        float ii = fmaxf(Air * rv[q] + Aii * iv[q] + oI, 0.f);
        float m = rr * rr + ii * ii;
        if (m > bm) { bm = m; brv = rr; biv = ii; }
    }
    int k = (c * PH2 + ph) * PW2 + pw;
    P2Tr[k * BB + b] = brv;
    P2Ti[k * BB + b] = biv;
}

// ============================================================
// complex GEMM: out[64][512] += XT[k][64] (x) W[n][k]
// ============================================================
#define GKC 32
__global__ __launch_bounds__(256) void k_gemm_cplx(
                            const float* __restrict__ XTr, const float* __restrict__ XTi,
                            const float* __restrict__ Wr, const float* __restrict__ Wi,
                            float* __restrict__ outR, float* __restrict__ outI,
                            int K, int nStages, int nSplit) {
    __shared__ float lxr[GKC][64], lxi[GKC][64];
    __shared__ float lwr[GKC][68], lwi[GKC][68];
    int tid = threadIdx.x;
    int n0 = blockIdx.x * 64;
    int split = blockIdx.y;
    int bq = tid & 15, nq = tid >> 4;
    int nl = tid & 63, kg = tid >> 6;
    float accR[4][4] = {}, accI[4][4] = {};
    for (int st = split; st < nStages; st += nSplit) {
        int k0 = st * GKC;
        __syncthreads();
#pragma unroll
        for (int u = 0; u < 2; u++) {
            int p = u * 1024 + tid * 4;
            int g = k0 * 64 + p;
            float4 vr = make_float4(0.f, 0.f, 0.f, 0.f), vi = vr;
            if (g < K * 64) {
                vr = *(const float4*)(XTr + g);
                vi = *(const float4*)(XTi + g);
            }
            *(float4*)&((float*)lxr)[p] = vr;
            *(float4*)&((float*)lxi)[p] = vi;
        }
#pragma unroll
        for (int u = 0; u < 2; u++) {
            int koff = kg * 8 + u * 4;
            int k = k0 + koff;
            float4 vr = make_float4(0.f, 0.f, 0.f, 0.f), vi = vr;
            if (k < K) {
                vr = *(const float4*)(Wr + (size_t)(n0 + nl) * K + k);
                vi = *(const float4*)(Wi + (size_t)(n0 + nl) * K + k);
            }
            lwr[koff + 0][nl] = vr.x; lwr[koff + 1][nl] = vr.y;
            lwr[koff + 2][nl] = vr.z; lwr[koff + 3][nl] = vr.w;
            lwi[koff + 0][nl] = vi.x; lwi[koff + 1][nl] = vi.y;
            lwi[koff + 2][nl] = vi.z; lwi[koff + 3][nl] = vi.w;
        }
        __syncthreads();
#pragma unroll 4
        for (int kk = 0; kk < GKC; kk++) {
            float4 xr4 = *(const float4*)&lxr[kk][bq * 4];
            float4 xi4 = *(const float4*)&lxi[kk][bq * 4];
            float4 wr4 = *(const float4*)&lwr[kk][nq * 4];
            float4 wi4 = *(const float4*)&lwi[kk][nq * 4];
            float xra[4] = {xr4.x, xr4.y, xr4.z, xr4.w};
            float xia[4] = {xi4.x, xi4.y, xi4.z, xi4.w};
            float wra[4] = {wr4.x, wr4.y, wr4.z, wr4.w};
            float wia[4] = {wi4.x, wi4.y, wi4.z, wi4.w};
#pragma unroll
            for (int i = 0; i < 4; i++)
#pragma unroll
                for (int j = 0; j < 4; j++) {
                    accR[i][j] += xra[i] * wra[j] - xia[i] * wia[j];
                    accI[i][j] += xra[i] * wia[j] + xia[i] * wra[j];
                }
        }
    }
#pragma unroll
    for (int i = 0; i < 4; i++)
#pragma unroll
        for (int j = 0; j < 4; j++) {
            int b = bq * 4 + i;
            int n = n0 + nq * 4 + j;
            unsafeAtomicAdd(&outR[b * HID + n], accR[i][j]);
            unsafeAtomicAdd(&outI[b * HID + n], accI[i][j]);
        }
}

// ============================================================
// FC BN coef (batch axis only, N=64), C features
// ============================================================
__global__ __launch_bounds__(256) void k_bnfc_coef(
                            const float* __restrict__ inr, const float* __restrict__ ini, int C,
                            const float* __restrict__ grr, const float* __restrict__ gri,
                            const float* __restrict__ gii,
                            const float* __restrict__ ber, const float* __restrict__ bei,
                            float* __restrict__ coef) {
    int f = blockIdx.x * 256 + threadIdx.x;
    if (f >= C) return;
    double sr = 0, si = 0, srr = 0, sii = 0, sri = 0;
    for (int b = 0; b < BB; b++) {
        double r = inr[b * C + f], i = ini[b * C + f];
        sr += r; si += i; srr += r * r; sii += i * i; sri += r * i;
    }
    double invN = 1.0 / BB;
    double mr = sr * invN, mi = si * invN;
    double Vrr = srr * invN - mr * mr + EPSV;
    double Vii = sii * invN - mi * mi + EPSV;
    double Vri = sri * invN - mr * mi;
    double s = sqrt(Vrr * Vii - Vri * Vri);
    double t = sqrt(Vrr + Vii + 2.0 * s);
    double inv = 1.0 / (s * t);
    double Rrr = (Vii + s) * inv, Rii = (Vrr + s) * inv, Rri = -Vri * inv;
    double Grr = grr[f], Gri = gri[f], Gii = gii[f];
    double Arr = Grr * Rrr + Gri * Rri, Ari = Grr * Rri + Gri * Rii;
    double Air = Gri * Rrr + Gii * Rri, Aii = Gri * Rri + Gii * Rii;
    coef[f * 6 + 0] = (float)Arr;
    coef[f * 6 + 1] = (float)Ari;
    coef[f * 6 + 2] = (float)Air;
    coef[f * 6 + 3] = (float)Aii;
    coef[f * 6 + 4] = (float)((double)ber[f] - (Arr * mr + Ari * mi));
    coef[f * 6 + 5] = (float)((double)bei[f] - (Air * mr + Aii * mi));
}

// ============================================================
// FC BN apply + relu; optional transposed output [f][64]
// ============================================================
__global__ __launch_bounds__(256) void k_bnfc_apply(
                             const float* __restrict__ inr, const float* __restrict__ ini,
                             const float* __restrict__ coef,
                             float* __restrict__ outr, float* __restrict__ outi,
                             int C, int transposeOut) {
    int idx = blockIdx.x * 256 + threadIdx.x;
    if (idx >= BB * C) return;
    int f = idx % C;
    int b = idx / C;
    float r = inr[idx], i = ini[idx];
    float rr = fmaxf(coef[f * 6 + 0] * r + coef[f * 6 + 1] * i + coef[f * 6 + 4], 0.f);
    float ii = fmaxf(coef[f * 6 + 2] * r + coef[f * 6 + 3] * i + coef[f * 6 + 5], 0.f);
    if (transposeOut) { outr[f * BB + b] = rr; outi[f * BB + b] = ii; }
    else              { outr[idx] = rr;        outi[idx] = ii; }
}

// ============================================================
// classifier (512->10 complex) + |z|^2 + log_softmax
// ============================================================
__global__ __launch_bounds__(64) void k_classifier(
                             const float* __restrict__ xr, const float* __restrict__ xi,
                             const float* __restrict__ cwr, const float* __restrict__ cwi,
                             const float* __restrict__ cbr, const float* __restrict__ cbi,
                             float* __restrict__ out) {
    int b = blockIdx.x;
    int lane = threadIdx.x;
    __shared__ float z[NCLS];
    for (int cls = 0; cls < NCLS; cls++) {
        float ar = 0.f, ai = 0.f;
#pragma unroll
        for (int j = 0; j < 8; j++) {
            int k = j * 64 + lane;
            float xrv = xr[b * HID + k], xiv = xi[b * HID + k];
            float wr = cwr[cls * HID + k], wi = cwi[cls * HID + k];
            ar += xrv * wr - xiv * wi;
            ai += xrv * wi + xiv * wr;
        }
#pragma unroll
        for (int m = 32; m >= 1; m >>= 1) {
            ar += __shfl_xor(ar, m, 64);
            ai += __shfl_xor(ai, m, 64);
        }
        if (lane == 0) {
            float hr = ar + cbr[cls], hi = ai + cbi[cls];
            z[cls] = hr * hr + hi * hi;
        }
    }
    __syncthreads();
    if (lane == 0) {
        float mx = z[0];
#pragma unroll
        for (int c = 1; c < NCLS; c++) mx = fmaxf(mx, z[c]);
        float s = 0.f;
#pragma unroll
        for (int c = 0; c < NCLS; c++) s += expf(z[c] - mx);
        float ls = logf(s);
#pragma unroll
        for (int c = 0; c < NCLS; c++) out[b * NCLS + c] = z[c] - mx - ls;
    }
}

// ============================================================
extern "C" void kernel_launch(void* const* d_in, const int* in_sizes, int n_in,
                              void* d_out, int out_size, void* d_ws, size_t ws_size,
                              hipStream_t stream) {
    const float* x_re = (const float*)d_in[0];
    const float* x_im = (const float*)d_in[1];
    const float* w1r = (const float*)d_in[2];
    const float* w1i = (const float*)d_in[3];
    const float* b1r = (const float*)d_in[4];
    const float* b1i = (const float*)d_in[5];
    const float* g1rr = (const float*)d_in[6];
    const float* g1ri = (const float*)d_in[7];
    const float* g1ii = (const float*)d_in[8];
    const float* be1r = (const float*)d_in[9];
    const float* be1i = (const float*)d_in[10];
    const float* w2r = (const float*)d_in[11];
    const float* w2i = (const float*)d_in[12];
    const float* b2r = (const float*)d_in[13];
    const float* b2i = (const float*)d_in[14];
    const float* g2rr = (const float*)d_in[15];
    const float* g2ri = (const float*)d_in[16];
    const float* g2ii = (const float*)d_in[17];
    const float* be2r = (const float*)d_in[18];
    const float* be2i = (const float*)d_in[19];
    const float* f1wr = (const float*)d_in[20];
    const float* f1wi = (const float*)d_in[21];
    const float* f1br = (const float*)d_in[22];
    const float* f1bi = (const float*)d_in[23];
    const float* g3rr = (const float*)d_in[24];
    const float* g3ri = (const float*)d_in[25];
    const float* g3ii = (const float*)d_in[26];
    const float* be3r = (const float*)d_in[27];
    const float* be3i = (const float*)d_in[28];
    const float* f2wr = (const float*)d_in[29];
    const float* f2wi = (const float*)d_in[30];
    const float* f2br = (const float*)d_in[31];
    const float* f2bi = (const float*)d_in[32];
    const float* g4rr = (const float*)d_in[33];
    const float* g4ri = (const float*)d_in[34];
    const float* g4ii = (const float*)d_in[35];
    const float* be4r = (const float*)d_in[36];
    const float* be4i = (const float*)d_in[37];
    const float* cwr = (const float*)d_in[38];
    const float* cwi = (const float*)d_in[39];
    const float* cbr = (const float*)d_in[40];
    const float* cbi = (const float*)d_in[41];
    float* out = (float*)d_out;

    char* ws = (char*)d_ws;
    size_t off = 0;
    auto alloc = [&](size_t nbytes) -> void* {
        off = (off + 255) & ~(size_t)255;
        void* p = ws + off;
        off += nbytes;
        return p;
    };
    float* P1r   = (float*)alloc((size_t)BB * C1c * PH1 * PW1 * 4);
    float* P1i   = (float*)alloc((size_t)BB * C1c * PH1 * PW1 * 4);
    float* buf2r = (float*)alloc((size_t)BB * C2c * OH2 * OW2 * 4);
    float* buf2i = (float*)alloc((size_t)BB * C2c * OH2 * OW2 * 4);
    float* P2Tr  = (float*)alloc((size_t)FLAT * BB * 4);
    float* P2Ti  = (float*)alloc((size_t)FLAT * BB * 4);
    float* fc1r  = (float*)alloc((size_t)BB * HID * 4);
    float* fc1i  = (float*)alloc((size_t)BB * HID * 4);
    float* fc1aTr = (float*)alloc((size_t)HID * BB * 4);
    float* fc1aTi = (float*)alloc((size_t)HID * BB * 4);
    float* fc2r  = (float*)alloc((size_t)BB * HID * 4);
    float* fc2i  = (float*)alloc((size_t)BB * HID * 4);
    float* fc2ar = (float*)alloc((size_t)BB * HID * 4);
    float* fc2ai = (float*)alloc((size_t)BB * HID * 4);
    double* part1 = (double*)alloc((size_t)C1c * 5 * NB1 * 8);
    double* part2 = (double*)alloc((size_t)C2c * 5 * NB2 * 8);
    double* sums1 = (double*)alloc(C1c * 5 * 8);
    double* sums2 = (double*)alloc(C2c * 5 * 8);
    float* coef1 = (float*)alloc(C1c * 6 * 4);
    float* coef2 = (float*)alloc(C2c * 6 * 4);
    float* coefF1 = (float*)alloc(HID * 6 * 4);
    float* coefF2 = (float*)alloc(HID * 6 * 4);

    // 0) init
    k_init<<<128, 256, 0, stream>>>(fc1r, fc1i, fc2r, fc2i, f1br, f1bi, f2br, f2bi);
    // 1) conv1 stats partials
    k_conv1_stats<<<dim3(NB1, C1c), 256, 0, stream>>>(x_re, x_im, w1r, w1i, b1r, b1i, part1);
    k_part_reduce<<<C1c, 320, 0, stream>>>(part1, NB1, sums1);
    // 2) BN1 coefs
    k_bn_coef<<<1, 64, 0, stream>>>(sums1, C1c, 1.0 / ((double)BB * OH1 * OW1),
                                    g1rr, g1ri, g1ii, be1r, be1i, coef1);
    // 3) conv1 + BN + relu + pool -> P1
    k_conv1_apply_pool<<<dim3(728, C1c), 256, 0, stream>>>(x_re, x_im, w1r, w1i, b1r, b1i,
                                                           coef1, P1r, P1i);
    // 4) conv2 + store + stats partials (COG=2 x 2 rows -> grid (163,10))
    k_conv2_stats<<<dim3(NB2, C2c / COG), 256, 0, stream>>>(P1r, P1i, w2r, w2i, b2r, b2i,
                                                            buf2r, buf2i, part2);
    k_part_reduce<<<C2c, 320, 0, stream>>>(part2, NB2, sums2);
    // 5) BN2 coefs
    k_bn_coef<<<1, 64, 0, stream>>>(sums2, C2c, 1.0 / ((double)BB * OH2 * OW2),
                                    g2rr, g2ri, g2ii, be2r, be2i, coef2);
    // 6) BN2 + relu + pool -> P2T [26000][64]
    k_bn2_pool<<<6500, 256, 0, stream>>>(buf2r, buf2i, coef2, P2Tr, P2Ti);
    // 7) FC1 GEMM (K=26000, 813 stages, split 64)
    k_gemm_cplx<<<dim3(8, 64), 256, 0, stream>>>(P2Tr, P2Ti, f1wr, f1wi, fc1r, fc1i,
                                                 FLAT, 813, 64);
    // 8) BN3 coefs
    k_bnfc_coef<<<2, 256, 0, stream>>>(fc1r, fc1i, HID, g3rr, g3ri, g3ii, be3r, be3i, coefF1);
    // 9) BN3 apply + relu -> transposed [512][64]
    k_bnfc_apply<<<128, 256, 0, stream>>>(fc1r, fc1i, coefF1, fc1aTr, fc1aTi, HID, 1);
    // 10) FC2 GEMM (K=512, 16 stages, split 16)
    k_gemm_cplx<<<dim3(8, 16), 256, 0, stream>>>(fc1aTr, fc1aTi, f2wr, f2wi, fc2r, fc2i,
                                                 HID, 16, 16);
    // 11) BN4 coefs
    k_bnfc_coef<<<2, 256, 0, stream>>>(fc2r, fc2i, HID, g4rr, g4ri, g4ii, be4r, be4i, coefF2);
    // 12) BN4 apply + relu -> [64][512]
    k_bnfc_apply<<<128, 256, 0, stream>>>(fc2r, fc2i, coefF2, fc2ar, fc2ai, HID, 0);
    // 13) classifier + log_softmax
    k_classifier<<<64, 64, 0, stream>>>(fc2ar, fc2ai, cwr, cwi, cbr, cbi, out);
}

// Round 7
// 924.179 us; speedup vs baseline: 1.1634x; 1.1634x over previous
//
#include <hip/hip_runtime.h>
#include <math.h>

// ---------------- dims ----------------
#define BB 64
#define H1 116
#define W1 212
#define C1c 10
#define OH1 112
#define OW1 208
#define PH1 56
#define PW1 104
#define C2c 20
#define OH2 52
#define OW2 100
#define PH2 26
#define PW2 50
#define FLAT 26000
#define HID 512
#define NCLS 10
#define EPSV 1e-5
#define NB1 728          // conv1 stats blocks per channel (64*112*26 / 256)
#define NB2 325          // conv2 blocks per channel-group (64*52*25 / 256)
#define COG 2            // conv2 output channels per thread
// conv2 config history: COG=1/no-blocking = 362us; COG=5 -> 244 VGPR, 10% occ,
// 474us; COG=2+2rows+scalar-weights -> SGPR spill-loads, 156 VGPR, 504us.
// COG=2, 1 row, LDS weights (VGPR 120, 4 waves/SIMD) = 315us -- keep that shape.

// ============================================================
// init: bias-init FC accumulators
// ============================================================
__global__ __launch_bounds__(256) void k_init(
                       float* fc1r, float* fc1i, float* fc2r, float* fc2i,
                       const float* __restrict__ f1br, const float* __restrict__ f1bi,
                       const float* __restrict__ f2br, const float* __restrict__ f2bi) {
    int idx = blockIdx.x * 256 + threadIdx.x;
    if (idx < BB * HID) {
        int n = idx % HID;
        fc1r[idx] = f1br[n]; fc1i[idx] = f1bi[n];
        fc2r[idx] = f2br[n]; fc2i[idx] = f2bi[n];
    }
}

// ============================================================
// conv1 + stats partials. grid (728, 10), block 256.
// 8 outputs/thread: 3 aligned float4 window loads per row.
// f32 moment reduce, f64 only at partial write.
// ============================================================
__global__ __launch_bounds__(256) void k_conv1_stats(
                              const float* __restrict__ xr, const float* __restrict__ xi,
                              const float* __restrict__ w1r, const float* __restrict__ w1i,
                              const float* __restrict__ b1r, const float* __restrict__ b1i,
                              double* __restrict__ part) {
    __shared__ float swr[25], swi[25];
    __shared__ float red[4][5];
    int tid = threadIdx.x;
    int c = blockIdx.y;
    if (tid < 25) { swr[tid] = w1r[c * 25 + tid]; swi[tid] = w1i[c * 25 + tid]; }
    __syncthreads();
    int idx = blockIdx.x * 256 + tid;
    int wg = idx % 26;
    int h  = (idx / 26) % OH1;
    int b  = idx / (26 * OH1);
    int w0 = wg * 8;
    float br = b1r[c], bi = b1i[c];
    float yr[8], yi[8];
#pragma unroll
    for (int j = 0; j < 8; j++) { yr[j] = br; yi[j] = bi; }
    const float* xrb = xr + b * (H1 * W1);
    const float* xib = xi + b * (H1 * W1);
#pragma unroll
    for (int kh = 0; kh < 5; kh++) {
        float ar[12], ai[12];
        const float* pr = xrb + (h + kh) * W1 + w0;
        const float* pi = xib + (h + kh) * W1 + w0;
        *(float4*)&ar[0] = *(const float4*)pr;
        *(float4*)&ar[4] = *(const float4*)(pr + 4);
        *(float4*)&ar[8] = *(const float4*)(pr + 8);
        *(float4*)&ai[0] = *(const float4*)pi;
        *(float4*)&ai[4] = *(const float4*)(pi + 4);
        *(float4*)&ai[8] = *(const float4*)(pi + 8);
#pragma unroll
        for (int kw = 0; kw < 5; kw++) {
            float wrv = swr[kh * 5 + kw], wiv = swi[kh * 5 + kw];
#pragma unroll
            for (int j = 0; j < 8; j++) {
                float vr = ar[kw + j], vi = ai[kw + j];
                yr[j] += vr * wrv - vi * wiv;
                yi[j] += vr * wiv + vi * wrv;
            }
        }
    }
    float v[5] = {0.f, 0.f, 0.f, 0.f, 0.f};
#pragma unroll
    for (int j = 0; j < 8; j++) {
        float r = yr[j], i = yi[j];
        v[0] += r; v[1] += i; v[2] += r * r; v[3] += i * i; v[4] += r * i;
    }
#pragma unroll
    for (int m = 32; m >= 1; m >>= 1) {
#pragma unroll
        for (int q = 0; q < 5; q++) v[q] += __shfl_xor(v[q], m, 64);
    }
    if ((tid & 63) == 0) {
#pragma unroll
        for (int q = 0; q < 5; q++) red[tid >> 6][q] = v[q];
    }
    __syncthreads();
    if (tid == 0) {
#pragma unroll
        for (int q = 0; q < 5; q++)
            part[(c * 5 + q) * NB1 + blockIdx.x] =
                (double)red[0][q] + (double)red[1][q] + (double)red[2][q] + (double)red[3][q];
    }
}

// ============================================================
// reduce per-block partials -> sums[c*5+q]
// ============================================================
__global__ __launch_bounds__(320) void k_part_reduce(
                              const double* __restrict__ part, int NB,
                              double* __restrict__ sums) {
    int c = blockIdx.x;
    int q = threadIdx.x >> 6;
    int lane = threadIdx.x & 63;
    double s = 0.0;
    for (int b = lane; b < NB; b += 64) s += part[(c * 5 + q) * NB + b];
#pragma unroll
    for (int m = 32; m >= 1; m >>= 1) s += __shfl_xor(s, m, 64);
    if (lane == 0) sums[c * 5 + q] = s;
}

// ============================================================
// BN coefficients from double sums (conv layers)
// ============================================================
__global__ __launch_bounds__(64) void k_bn_coef(
                          const double* __restrict__ sums, int C, double invN,
                          const float* __restrict__ grr, const float* __restrict__ gri,
                          const float* __restrict__ gii,
                          const float* __restrict__ ber, const float* __restrict__ bei,
                          float* __restrict__ coef) {
    int c = threadIdx.x;
    if (c >= C) return;
    double sr = sums[c * 5 + 0], si = sums[c * 5 + 1];
    double srr = sums[c * 5 + 2], sii = sums[c * 5 + 3], sri = sums[c * 5 + 4];
    double mr = sr * invN, mi = si * invN;
    double Vrr = srr * invN - mr * mr + EPSV;
    double Vii = sii * invN - mi * mi + EPSV;
    double Vri = sri * invN - mr * mi;
    double s = sqrt(Vrr * Vii - Vri * Vri);
    double t = sqrt(Vrr + Vii + 2.0 * s);
    double inv = 1.0 / (s * t);
    double Rrr = (Vii + s) * inv, Rii = (Vrr + s) * inv, Rri = -Vri * inv;
    double Grr = grr[c], Gri = gri[c], Gii = gii[c];
    double Arr = Grr * Rrr + Gri * Rri, Ari = Grr * Rri + Gri * Rii;
    double Air = Gri * Rrr + Gii * Rri, Aii = Gri * Rri + Gii * Rii;
    coef[c * 6 + 0] = (float)Arr;
    coef[c * 6 + 1] = (float)Ari;
    coef[c * 6 + 2] = (float)Air;
    coef[c * 6 + 3] = (float)Aii;
    coef[c * 6 + 4] = (float)((double)ber[c] - (Arr * mr + Ari * mi));
    coef[c * 6 + 5] = (float)((double)bei[c] - (Air * mr + Aii * mi));
}

// ============================================================
// conv1 recompute + BN affine + relu + mag-pool -> P1 [b][c][56][104]
// grid (728, 10)
// ============================================================
__global__ __launch_bounds__(256) void k_conv1_apply_pool(
                                   const float* __restrict__ xr, const float* __restrict__ xi,
                                   const float* __restrict__ w1r, const float* __restrict__ w1i,
                                   const float* __restrict__ b1r, const float* __restrict__ b1i,
                                   const float* __restrict__ coef,
                                   float* __restrict__ P1r, float* __restrict__ P1i) {
    __shared__ float swr[25], swi[25];
    int tid = threadIdx.x;
    int c = blockIdx.y;
    if (tid < 25) { swr[tid] = w1r[c * 25 + tid]; swi[tid] = w1i[c * 25 + tid]; }
    __syncthreads();
    int idx = blockIdx.x * 256 + tid;
    int pwg = idx % 52;
    int ph  = (idx / 52) % PH1;
    int b   = idx / (52 * PH1);
    int h0 = 2 * ph, w0 = 4 * pwg;
    float br = b1r[c], bi = b1i[c];
    float yr[2][4], yi[2][4];
#pragma unroll
    for (int oi = 0; oi < 2; oi++)
#pragma unroll
        for (int j = 0; j < 4; j++) { yr[oi][j] = br; yi[oi][j] = bi; }
    const float* xrb = xr + b * (H1 * W1);
    const float* xib = xi + b * (H1 * W1);
#pragma unroll
    for (int r = 0; r < 6; r++) {
        float ar[8], ai[8];
        const float* pr = xrb + (h0 + r) * W1 + w0;
        const float* pi = xib + (h0 + r) * W1 + w0;
        *(float4*)&ar[0] = *(const float4*)pr;
        *(float4*)&ar[4] = *(const float4*)(pr + 4);
        *(float4*)&ai[0] = *(const float4*)pi;
        *(float4*)&ai[4] = *(const float4*)(pi + 4);
#pragma unroll
        for (int oi = 0; oi < 2; oi++) {
            int kh = r - oi;
            if (kh >= 0 && kh < 5) {
#pragma unroll
                for (int kw = 0; kw < 5; kw++) {
                    float wrv = swr[kh * 5 + kw], wiv = swi[kh * 5 + kw];
#pragma unroll
                    for (int j = 0; j < 4; j++) {
                        float vr = ar[kw + j], vi = ai[kw + j];
                        yr[oi][j] += vr * wrv - vi * wiv;
                        yi[oi][j] += vr * wiv + vi * wrv;
                    }
                }
            }
        }
    }
    float Arr = coef[c * 6 + 0], Ari = coef[c * 6 + 1];
    float Air = coef[c * 6 + 2], Aii = coef[c * 6 + 3];
    float oR = coef[c * 6 + 4], oI = coef[c * 6 + 5];
    float bm0 = -1.f, br0 = 0.f, bi0 = 0.f;
    float bm1 = -1.f, br1 = 0.f, bi1 = 0.f;
#pragma unroll
    for (int oi = 0; oi < 2; oi++) {
#pragma unroll
        for (int j = 0; j < 4; j++) {
            float rr = fmaxf(Arr * yr[oi][j] + Ari * yi[oi][j] + oR, 0.f);
            float ii = fmaxf(Air * yr[oi][j] + Aii * yi[oi][j] + oI, 0.f);
            float m = rr * rr + ii * ii;
            if (j < 2) { if (m > bm0) { bm0 = m; br0 = rr; bi0 = ii; } }
            else       { if (m > bm1) { bm1 = m; br1 = rr; bi1 = ii; } }
        }
    }
    int pbase = ((b * C1c + c) * PH1 + ph) * PW1 + 2 * pwg;
    *(float2*)&P1r[pbase] = make_float2(br0, br1);
    *(float2*)&P1i[pbase] = make_float2(bi0, bi1);
}

// ============================================================
// conv2: P1 -> buf2 [b][c][52][100] (stored) + stats partials
// grid (325, 10): COG=2 channels x 4 pixels per thread (round-5 shape).
// LDS weights repacked [g][cin][kh][8] so the 5-tap read is
// 1x ds_read_b128 + 1x ds_read_b32 (wave-uniform -> broadcast).
// ============================================================
__global__ __launch_bounds__(256) void k_conv2_stats(
                              const float* __restrict__ P1r, const float* __restrict__ P1i,
                              const float* __restrict__ w2r, const float* __restrict__ w2i,
                              const float* __restrict__ b2r, const float* __restrict__ b2i,
                              float* __restrict__ buf2r, float* __restrict__ buf2i,
                              double* __restrict__ part) {
    __shared__ float swr[COG * C1c * 5 * 8], swi[COG * C1c * 5 * 8];
    __shared__ float red[4][5];
    int tid = threadIdx.x;
    int cg = blockIdx.y;                 // couts cg*COG .. cg*COG+COG-1
    if (tid < 250) {
        int cin = tid / 25, rem = tid % 25, kh = rem / 5, kw = rem % 5;
#pragma unroll
        for (int g = 0; g < COG; g++) {
            int dst = ((g * C1c + cin) * 5 + kh) * 8 + kw;
            swr[dst] = w2r[(cg * COG + g) * 250 + tid];
            swi[dst] = w2i[(cg * COG + g) * 250 + tid];
        }
    }
    __syncthreads();
    int idx = blockIdx.x * 256 + tid;
    int wg = idx % 25;
    int h  = (idx / 25) % OH2;
    int b  = idx / (25 * OH2);
    int w0 = 4 * wg;
    float yr[COG][4], yi[COG][4];
#pragma unroll
    for (int g = 0; g < COG; g++) {
        float brv = b2r[cg * COG + g], biv = b2i[cg * COG + g];
#pragma unroll
        for (int j = 0; j < 4; j++) { yr[g][j] = brv; yi[g][j] = biv; }
    }
    for (int cin = 0; cin < C1c; cin++) {
        const float* pr = P1r + ((b * C1c + cin) * PH1 + h) * PW1 + w0;
        const float* pi = P1i + ((b * C1c + cin) * PH1 + h) * PW1 + w0;
#pragma unroll
        for (int kh = 0; kh < 5; kh++) {
            float ar[8], ai[8];
            *(float4*)&ar[0] = *(const float4*)(pr + kh * PW1);
            *(float4*)&ar[4] = *(const float4*)(pr + kh * PW1 + 4);
            *(float4*)&ai[0] = *(const float4*)(pi + kh * PW1);
            *(float4*)&ai[4] = *(const float4*)(pi + kh * PW1 + 4);
#pragma unroll
            for (int g = 0; g < COG; g++) {
                int wb = ((g * C1c + cin) * 5 + kh) * 8;
                float4 wr4 = *(const float4*)&swr[wb];
                float4 wi4 = *(const float4*)&swi[wb];
                float wra[5] = {wr4.x, wr4.y, wr4.z, wr4.w, swr[wb + 4]};
                float wia[5] = {wi4.x, wi4.y, wi4.z, wi4.w, swi[wb + 4]};
#pragma unroll
                for (int kw = 0; kw < 5; kw++) {
                    float wrv = wra[kw], wiv = wia[kw];
#pragma unroll
                    for (int j = 0; j < 4; j++) {
                        float vr = ar[kw + j], vi = ai[kw + j];
                        yr[g][j] += vr * wrv - vi * wiv;
                        yi[g][j] += vr * wiv + vi * wrv;
                    }
                }
            }
        }
    }
#pragma unroll
    for (int g = 0; g < COG; g++) {
        int ob = ((b * C2c + cg * COG + g) * OH2 + h) * OW2 + w0;
        *(float4*)&buf2r[ob] = make_float4(yr[g][0], yr[g][1], yr[g][2], yr[g][3]);
        *(float4*)&buf2i[ob] = make_float4(yi[g][0], yi[g][1], yi[g][2], yi[g][3]);
    }
    // stats: f32 per-wave reduce, f64 only at partial write
    for (int g = 0; g < COG; g++) {
        float v[5] = {0.f, 0.f, 0.f, 0.f, 0.f};
#pragma unroll
        for (int j = 0; j < 4; j++) {
            float r = yr[g][j], i = yi[g][j];
            v[0] += r; v[1] += i; v[2] += r * r; v[3] += i * i; v[4] += r * i;
        }
#pragma unroll
        for (int m = 32; m >= 1; m >>= 1) {
#pragma unroll
            for (int q = 0; q < 5; q++) v[q] += __shfl_xor(v[q], m, 64);
        }
        if ((tid & 63) == 0) {
#pragma unroll
            for (int q = 0; q < 5; q++) red[tid >> 6][q] = v[q];
        }
        __syncthreads();
        if (tid == 0) {
            int c = cg * COG + g;
#pragma unroll
            for (int q = 0; q < 5; q++)
                part[(c * 5 + q) * NB2 + blockIdx.x] =
                    (double)red[0][q] + (double)red[1][q] + (double)red[2][q] + (double)red[3][q];
        }
        __syncthreads();
    }
}

// ============================================================
// BN2 affine + relu + mag-pool, write transposed P2T [k=26000][b=64]
// ============================================================
__global__ __launch_bounds__(256) void k_bn2_pool(
                           const float* __restrict__ buf2r, const float* __restrict__ buf2i,
                           const float* __restrict__ coef,
                           float* __restrict__ P2Tr, float* __restrict__ P2Ti) {
    int idx = blockIdx.x * 256 + threadIdx.x;
    int pw = idx % PW2;
    int ph = (idx / PW2) % PH2;
    int c  = (idx / (PW2 * PH2)) % C2c;
    int b  = idx / (PW2 * PH2 * C2c);
    float Arr = coef[c * 6 + 0], Ari = coef[c * 6 + 1];
    float Air = coef[c * 6 + 2], Aii = coef[c * 6 + 3];
    float oR = coef[c * 6 + 4], oI = coef[c * 6 + 5];
    int ib = ((b * C2c + c) * OH2 + 2 * ph) * OW2 + 2 * pw;
    float rv[4], iv[4];
    rv[0] = buf2r[ib];           iv[0] = buf2i[ib];
    rv[1] = buf2r[ib + 1];       iv[1] = buf2i[ib + 1];
    rv[2] = buf2r[ib + OW2];     iv[2] = buf2i[ib + OW2];
    rv[3] = buf2r[ib + OW2 + 1]; iv[3] = buf2i[ib + OW2 + 1];
    float bm = -1.f, brv = 0.f, biv = 0.f;
#pragma unroll
    for (int q = 0; q < 4; q++) {
        float rr = fmaxf(Arr * rv[q] + Ari * iv[q] + oR, 0.f);
        float ii = fmaxf(Air * rv[q] + Aii * iv[q] + oI, 0.f);
        float m = rr * rr + ii * ii;
        if (m > bm) { bm = m; brv = rr; biv = ii; }
    }
    int k = (c * PH2 + ph) * PW2 + pw;
    P2Tr[k * BB + b] = brv;
    P2Ti[k * BB + b] = biv;
}

// ============================================================
// complex GEMM: out[64][512] += XT[k][64] (x) W[n][k]
// ============================================================
#define GKC 32
__global__ __launch_bounds__(256) void k_gemm_cplx(
                            const float* __restrict__ XTr, const float* __restrict__ XTi,
                            const float* __restrict__ Wr, const float* __restrict__ Wi,
                            float* __restrict__ outR, float* __restrict__ outI,
                            int K, int nStages, int nSplit) {
    __shared__ float lxr[GKC][64], lxi[GKC][64];
    __shared__ float lwr[GKC][68], lwi[GKC][68];
    int tid = threadIdx.x;
    int n0 = blockIdx.x * 64;
    int split = blockIdx.y;
    int bq = tid & 15, nq = tid >> 4;
    int nl = tid & 63, kg = tid >> 6;
    float accR[4][4] = {}, accI[4][4] = {};
    for (int st = split; st < nStages; st += nSplit) {
        int k0 = st * GKC;
        __syncthreads();
#pragma unroll
        for (int u = 0; u < 2; u++) {
            int p = u * 1024 + tid * 4;
            int g = k0 * 64 + p;
            float4 vr = make_float4(0.f, 0.f, 0.f, 0.f), vi = vr;
            if (g < K * 64) {
                vr = *(const float4*)(XTr + g);
                vi = *(const float4*)(XTi + g);
            }
            *(float4*)&((float*)lxr)[p] = vr;
            *(float4*)&((float*)lxi)[p] = vi;
        }
#pragma unroll
        for (int u = 0; u < 2; u++) {
            int koff = kg * 8 + u * 4;
            int k = k0 + koff;
            float4 vr = make_float4(0.f, 0.f, 0.f, 0.f), vi = vr;
            if (k < K) {
                vr = *(const float4*)(Wr + (size_t)(n0 + nl) * K + k);
                vi = *(const float4*)(Wi + (size_t)(n0 + nl) * K + k);
            }
            lwr[koff + 0][nl] = vr.x; lwr[koff + 1][nl] = vr.y;
            lwr[koff + 2][nl] = vr.z; lwr[koff + 3][nl] = vr.w;
            lwi[koff + 0][nl] = vi.x; lwi[koff + 1][nl] = vi.y;
            lwi[koff + 2][nl] = vi.z; lwi[koff + 3][nl] = vi.w;
        }
        __syncthreads();
#pragma unroll 4
        for (int kk = 0; kk < GKC; kk++) {
            float4 xr4 = *(const float4*)&lxr[kk][bq * 4];
            float4 xi4 = *(const float4*)&lxi[kk][bq * 4];
            float4 wr4 = *(const float4*)&lwr[kk][nq * 4];
            float4 wi4 = *(const float4*)&lwi[kk][nq * 4];
            float xra[4] = {xr4.x, xr4.y, xr4.z, xr4.w};
            float xia[4] = {xi4.x, xi4.y, xi4.z, xi4.w};
            float wra[4] = {wr4.x, wr4.y, wr4.z, wr4.w};
            float wia[4] = {wi4.x, wi4.y, wi4.z, wi4.w};
#pragma unroll
            for (int i = 0; i < 4; i++)
#pragma unroll
                for (int j = 0; j < 4; j++) {
                    accR[i][j] += xra[i] * wra[j] - xia[i] * wia[j];
                    accI[i][j] += xra[i] * wia[j] + xia[i] * wra[j];
                }
        }
    }
#pragma unroll
    for (int i = 0; i < 4; i++)
#pragma unroll
        for (int j = 0; j < 4; j++) {
            int b = bq * 4 + i;
            int n = n0 + nq * 4 + j;
            unsafeAtomicAdd(&outR[b * HID + n], accR[i][j]);
            unsafeAtomicAdd(&outI[b * HID + n], accI[i][j]);
        }
}

// ============================================================
// FC BN coef (batch axis only, N=64), C features
// ============================================================
__global__ __launch_bounds__(256) void k_bnfc_coef(
                            const float* __restrict__ inr, const float* __restrict__ ini, int C,
                            const float* __restrict__ grr, const float* __restrict__ gri,
                            const float* __restrict__ gii,
                            const float* __restrict__ ber, const float* __restrict__ bei,
                            float* __restrict__ coef) {
    int f = blockIdx.x * 256 + threadIdx.x;
    if (f >= C) return;
    double sr = 0, si = 0, srr = 0, sii = 0, sri = 0;
    for (int b = 0; b < BB; b++) {
        double r = inr[b * C + f], i = ini[b * C + f];
        sr += r; si += i; srr += r * r; sii += i * i; sri += r * i;
    }
    double invN = 1.0 / BB;
    double mr = sr * invN, mi = si * invN;
    double Vrr = srr * invN - mr * mr + EPSV;
    double Vii = sii * invN - mi * mi + EPSV;
    double Vri = sri * invN - mr * mi;
    double s = sqrt(Vrr * Vii - Vri * Vri);
    double t = sqrt(Vrr + Vii + 2.0 * s);
    double inv = 1.0 / (s * t);
    double Rrr = (Vii + s) * inv, Rii = (Vrr + s) * inv, Rri = -Vri * inv;
    double Grr = grr[f], Gri = gri[f], Gii = gii[f];
    double Arr = Grr * Rrr + Gri * Rri, Ari = Grr * Rri + Gri * Rii;
    double Air = Gri * Rrr + Gii * Rri, Aii = Gri * Rri + Gii * Rii;
    coef[f * 6 + 0] = (float)Arr;
    coef[f * 6 + 1] = (float)Ari;
    coef[f * 6 + 2] = (float)Air;
    coef[f * 6 + 3] = (float)Aii;
    coef[f * 6 + 4] = (float)((double)ber[f] - (Arr * mr + Ari * mi));
    coef[f * 6 + 5] = (float)((double)bei[f] - (Air * mr + Aii * mi));
}

// ============================================================
// FC BN apply + relu; optional transposed output [f][64]
// ============================================================
__global__ __launch_bounds__(256) void k_bnfc_apply(
                             const float* __restrict__ inr, const float* __restrict__ ini,
                             const float* __restrict__ coef,
                             float* __restrict__ outr, float* __restrict__ outi,
                             int C, int transposeOut) {
    int idx = blockIdx.x * 256 + threadIdx.x;
    if (idx >= BB * C) return;
    int f = idx % C;
    int b = idx / C;
    float r = inr[idx], i = ini[idx];
    float rr = fmaxf(coef[f * 6 + 0] * r + coef[f * 6 + 1] * i + coef[f * 6 + 4], 0.f);
    float ii = fmaxf(coef[f * 6 + 2] * r + coef[f * 6 + 3] * i + coef[f * 6 + 5], 0.f);
    if (transposeOut) { outr[f * BB + b] = rr; outi[f * BB + b] = ii; }
    else              { outr[idx] = rr;        outi[idx] = ii; }
}

// ============================================================
// classifier (512->10 complex) + |z|^2 + log_softmax
// ============================================================
__global__ __launch_bounds__(64) void k_classifier(
                             const float* __restrict__ xr, const float* __restrict__ xi,
                             const float* __restrict__ cwr, const float* __restrict__ cwi,
                             const float* __restrict__ cbr, const float* __restrict__ cbi,
                             float* __restrict__ out) {
    int b = blockIdx.x;
    int lane = threadIdx.x;
    __shared__ float z[NCLS];
    for (int cls = 0; cls < NCLS; cls++) {
        float ar = 0.f, ai = 0.f;
#pragma unroll
        for (int j = 0; j < 8; j++) {
            int k = j * 64 + lane;
            float xrv = xr[b * HID + k], xiv = xi[b * HID + k];
            float wr = cwr[cls * HID + k], wi = cwi[cls * HID + k];
            ar += xrv * wr - xiv * wi;
            ai += xrv * wi + xiv * wr;
        }
#pragma unroll
        for (int m = 32; m >= 1; m >>= 1) {
            ar += __shfl_xor(ar, m, 64);
            ai += __shfl_xor(ai, m, 64);
        }
        if (lane == 0) {
            float hr = ar + cbr[cls], hi = ai + cbi[cls];
            z[cls] = hr * hr + hi * hi;
        }
    }
    __syncthreads();
    if (lane == 0) {
        float mx = z[0];
#pragma unroll
        for (int c = 1; c < NCLS; c++) mx = fmaxf(mx, z[c]);
        float s = 0.f;
#pragma unroll
        for (int c = 0; c < NCLS; c++) s += expf(z[c] - mx);
        float ls = logf(s);
#pragma unroll
        for (int c = 0; c < NCLS; c++) out[b * NCLS + c] = z[c] - mx - ls;
    }
}

// ============================================================
extern "C" void kernel_launch(void* const* d_in, const int* in_sizes, int n_in,
                              void* d_out, int out_size, void* d_ws, size_t ws_size,
                              hipStream_t stream) {
    const float* x_re = (const float*)d_in[0];
    const float* x_im = (const float*)d_in[1];
    const float* w1r = (const float*)d_in[2];
    const float* w1i = (const float*)d_in[3];
    const float* b1r = (const float*)d_in[4];
    const float* b1i = (const float*)d_in[5];
    const float* g1rr = (const float*)d_in[6];
    const float* g1ri = (const float*)d_in[7];
    const float* g1ii = (const float*)d_in[8];
    const float* be1r = (const float*)d_in[9];
    const float* be1i = (const float*)d_in[10];
    const float* w2r = (const float*)d_in[11];
    const float* w2i = (const float*)d_in[12];
    const float* b2r = (const float*)d_in[13];
    const float* b2i = (const float*)d_in[14];
    const float* g2rr = (const float*)d_in[15];
    const float* g2ri = (const float*)d_in[16];
    const float* g2ii = (const float*)d_in[17];
    const float* be2r = (const float*)d_in[18];
    const float* be2i = (const float*)d_in[19];
    const float* f1wr = (const float*)d_in[20];
    const float* f1wi = (const float*)d_in[21];
    const float* f1br = (const float*)d_in[22];
    const float* f1bi = (const float*)d_in[23];
    const float* g3rr = (const float*)d_in[24];
    const float* g3ri = (const float*)d_in[25];
    const float* g3ii = (const float*)d_in[26];
    const float* be3r = (const float*)d_in[27];
    const float* be3i = (const float*)d_in[28];
    const float* f2wr = (const float*)d_in[29];
    const float* f2wi = (const float*)d_in[30];
    const float* f2br = (const float*)d_in[31];
    const float* f2bi = (const float*)d_in[32];
    const float* g4rr = (const float*)d_in[33];
    const float* g4ri = (const float*)d_in[34];
    const float* g4ii = (const float*)d_in[35];
    const float* be4r = (const float*)d_in[36];
    const float* be4i = (const float*)d_in[37];
    const float* cwr = (const float*)d_in[38];
    const float* cwi = (const float*)d_in[39];
    const float* cbr = (const float*)d_in[40];
    const float* cbi = (const float*)d_in[41];
    float* out = (float*)d_out;

    char* ws = (char*)d_ws;
    size_t off = 0;
    auto alloc = [&](size_t nbytes) -> void* {
        off = (off + 255) & ~(size_t)255;
        void* p = ws + off;
        off += nbytes;
        return p;
    };
    float* P1r   = (float*)alloc((size_t)BB * C1c * PH1 * PW1 * 4);
    float* P1i   = (float*)alloc((size_t)BB * C1c * PH1 * PW1 * 4);
    float* buf2r = (float*)alloc((size_t)BB * C2c * OH2 * OW2 * 4);
    float* buf2i = (float*)alloc((size_t)BB * C2c * OH2 * OW2 * 4);
    float* P2Tr  = (float*)alloc((size_t)FLAT * BB * 4);
    float* P2Ti  = (float*)alloc((size_t)FLAT * BB * 4);
    float* fc1r  = (float*)alloc((size_t)BB * HID * 4);
    float* fc1i  = (float*)alloc((size_t)BB * HID * 4);
    float* fc1aTr = (float*)alloc((size_t)HID * BB * 4);
    float* fc1aTi = (float*)alloc((size_t)HID * BB * 4);
    float* fc2r  = (float*)alloc((size_t)BB * HID * 4);
    float* fc2i  = (float*)alloc((size_t)BB * HID * 4);
    float* fc2ar = (float*)alloc((size_t)BB * HID * 4);
    float* fc2ai = (float*)alloc((size_t)BB * HID * 4);
    double* part1 = (double*)alloc((size_t)C1c * 5 * NB1 * 8);
    double* part2 = (double*)alloc((size_t)C2c * 5 * NB2 * 8);
    double* sums1 = (double*)alloc(C1c * 5 * 8);
    double* sums2 = (double*)alloc(C2c * 5 * 8);
    float* coef1 = (float*)alloc(C1c * 6 * 4);
    float* coef2 = (float*)alloc(C2c * 6 * 4);
    float* coefF1 = (float*)alloc(HID * 6 * 4);
    float* coefF2 = (float*)alloc(HID * 6 * 4);

    // 0) init
    k_init<<<128, 256, 0, stream>>>(fc1r, fc1i, fc2r, fc2i, f1br, f1bi, f2br, f2bi);
    // 1) conv1 stats partials (8-wide)
    k_conv1_stats<<<dim3(NB1, C1c), 256, 0, stream>>>(x_re, x_im, w1r, w1i, b1r, b1i, part1);
    k_part_reduce<<<C1c, 320, 0, stream>>>(part1, NB1, sums1);
    // 2) BN1 coefs
    k_bn_coef<<<1, 64, 0, stream>>>(sums1, C1c, 1.0 / ((double)BB * OH1 * OW1),
                                    g1rr, g1ri, g1ii, be1r, be1i, coef1);
    // 3) conv1 + BN + relu + pool -> P1
    k_conv1_apply_pool<<<dim3(728, C1c), 256, 0, stream>>>(x_re, x_im, w1r, w1i, b1r, b1i,
                                                           coef1, P1r, P1i);
    // 4) conv2 + store + stats partials (COG=2, 1 row -> grid (325,10))
    k_conv2_stats<<<dim3(NB2, C2c / COG), 256, 0, stream>>>(P1r, P1i, w2r, w2i, b2r, b2i,
                                                            buf2r, buf2i, part2);
    k_part_reduce<<<C2c, 320, 0, stream>>>(part2, NB2, sums2);
    // 5) BN2 coefs
    k_bn_coef<<<1, 64, 0, stream>>>(sums2, C2c, 1.0 / ((double)BB * OH2 * OW2),
                                    g2rr, g2ri, g2ii, be2r, be2i, coef2);
    // 6) BN2 + relu + pool -> P2T [26000][64]
    k_bn2_pool<<<6500, 256, 0, stream>>>(buf2r, buf2i, coef2, P2Tr, P2Ti);
    // 7) FC1 GEMM (K=26000, 813 stages, split 64)
    k_gemm_cplx<<<dim3(8, 64), 256, 0, stream>>>(P2Tr, P2Ti, f1wr, f1wi, fc1r, fc1i,
                                                 FLAT, 813, 64);
    // 8) BN3 coefs
    k_bnfc_coef<<<2, 256, 0, stream>>>(fc1r, fc1i, HID, g3rr, g3ri, g3ii, be3r, be3i, coefF1);
    // 9) BN3 apply + relu -> transposed [512][64]
    k_bnfc_apply<<<128, 256, 0, stream>>>(fc1r, fc1i, coefF1, fc1aTr, fc1aTi, HID, 1);
    // 10) FC2 GEMM (K=512, 16 stages, split 16)
    k_gemm_cplx<<<dim3(8, 16), 256, 0, stream>>>(fc1aTr, fc1aTi, f2wr, f2wi, fc2r, fc2i,
                                                 HID, 16, 16);
    // 11) BN4 coefs
    k_bnfc_coef<<<2, 256, 0, stream>>>(fc2r, fc2i, HID, g4rr, g4ri, g4ii, be4r, be4i, coefF2);
    // 12) BN4 apply + relu -> [64][512]
    k_bnfc_apply<<<128, 256, 0, stream>>>(fc2r, fc2i, coefF2, fc2ar, fc2ai, HID, 0);
    // 13) classifier + log_softmax
    k_classifier<<<64, 64, 0, stream>>>(fc2ar, fc2ai, cwr, cwi, cbr, cbi, out);
}

// Round 8
// 921.083 us; speedup vs baseline: 1.1673x; 1.0034x over previous
//
#include <hip/hip_runtime.h>
#include <math.h>

// ---------------- dims ----------------
#define BB 64
#define H1 116
#define W1 212
#define C1c 10
#define OH1 112
#define OW1 208
#define PH1 56
#define PW1 104
#define C2c 20
#define OH2 52
#define OW2 100
#define PH2 26
#define PW2 50
#define FLAT 26000
#define HID 512
#define NCLS 10
#define EPSV 1e-5
#define NB1 728          // conv1 stats blocks per channel (64*112*26 / 256)
#define NB2 325          // conv2 pixel-blocks (64*52*25 / 256)
#define COG 2            // conv2 output channels per thread
// conv2 config history: COG=1 = 362us; COG=5 -> 244 VGPR / 10% occ = 474us;
// COG=2+2rows+scalar-weights -> SGPR-load stalls = 504us; COG=2 + b128 weight
// repack -> v_mov overhead = 358us. BEST: COG=2, 1 row, per-tap LDS broadcast
// reads (round 5) = 315us. This round keeps that body and swaps the grid so
// the 10 cg-blocks sharing one P1 slice dispatch consecutively (L2 locality).

// ============================================================
// init: bias-init FC accumulators
// ============================================================
__global__ __launch_bounds__(256) void k_init(
                       float* fc1r, float* fc1i, float* fc2r, float* fc2i,
                       const float* __restrict__ f1br, const float* __restrict__ f1bi,
                       const float* __restrict__ f2br, const float* __restrict__ f2bi) {
    int idx = blockIdx.x * 256 + threadIdx.x;
    if (idx < BB * HID) {
        int n = idx % HID;
        fc1r[idx] = f1br[n]; fc1i[idx] = f1bi[n];
        fc2r[idx] = f2br[n]; fc2i[idx] = f2bi[n];
    }
}

// ============================================================
// conv1 + stats partials. grid (728, 10), block 256.
// 8 outputs/thread: 3 aligned float4 window loads per row.
// ============================================================
__global__ __launch_bounds__(256) void k_conv1_stats(
                              const float* __restrict__ xr, const float* __restrict__ xi,
                              const float* __restrict__ w1r, const float* __restrict__ w1i,
                              const float* __restrict__ b1r, const float* __restrict__ b1i,
                              double* __restrict__ part) {
    __shared__ float swr[25], swi[25];
    __shared__ float red[4][5];
    int tid = threadIdx.x;
    int c = blockIdx.y;
    if (tid < 25) { swr[tid] = w1r[c * 25 + tid]; swi[tid] = w1i[c * 25 + tid]; }
    __syncthreads();
    int idx = blockIdx.x * 256 + tid;
    int wg = idx % 26;
    int h  = (idx / 26) % OH1;
    int b  = idx / (26 * OH1);
    int w0 = wg * 8;
    float br = b1r[c], bi = b1i[c];
    float yr[8], yi[8];
#pragma unroll
    for (int j = 0; j < 8; j++) { yr[j] = br; yi[j] = bi; }
    const float* xrb = xr + b * (H1 * W1);
    const float* xib = xi + b * (H1 * W1);
#pragma unroll
    for (int kh = 0; kh < 5; kh++) {
        float ar[12], ai[12];
        const float* pr = xrb + (h + kh) * W1 + w0;
        const float* pi = xib + (h + kh) * W1 + w0;
        *(float4*)&ar[0] = *(const float4*)pr;
        *(float4*)&ar[4] = *(const float4*)(pr + 4);
        *(float4*)&ar[8] = *(const float4*)(pr + 8);
        *(float4*)&ai[0] = *(const float4*)pi;
        *(float4*)&ai[4] = *(const float4*)(pi + 4);
        *(float4*)&ai[8] = *(const float4*)(pi + 8);
#pragma unroll
        for (int kw = 0; kw < 5; kw++) {
            float wrv = swr[kh * 5 + kw], wiv = swi[kh * 5 + kw];
#pragma unroll
            for (int j = 0; j < 8; j++) {
                float vr = ar[kw + j], vi = ai[kw + j];
                yr[j] += vr * wrv - vi * wiv;
                yi[j] += vr * wiv + vi * wrv;
            }
        }
    }
    float v[5] = {0.f, 0.f, 0.f, 0.f, 0.f};
#pragma unroll
    for (int j = 0; j < 8; j++) {
        float r = yr[j], i = yi[j];
        v[0] += r; v[1] += i; v[2] += r * r; v[3] += i * i; v[4] += r * i;
    }
#pragma unroll
    for (int m = 32; m >= 1; m >>= 1) {
#pragma unroll
        for (int q = 0; q < 5; q++) v[q] += __shfl_xor(v[q], m, 64);
    }
    if ((tid & 63) == 0) {
#pragma unroll
        for (int q = 0; q < 5; q++) red[tid >> 6][q] = v[q];
    }
    __syncthreads();
    if (tid == 0) {
#pragma unroll
        for (int q = 0; q < 5; q++)
            part[(c * 5 + q) * NB1 + blockIdx.x] =
                (double)red[0][q] + (double)red[1][q] + (double)red[2][q] + (double)red[3][q];
    }
}

// ============================================================
// reduce per-block partials -> sums[c*5+q]
// ============================================================
__global__ __launch_bounds__(320) void k_part_reduce(
                              const double* __restrict__ part, int NB,
                              double* __restrict__ sums) {
    int c = blockIdx.x;
    int q = threadIdx.x >> 6;
    int lane = threadIdx.x & 63;
    double s = 0.0;
    for (int b = lane; b < NB; b += 64) s += part[(c * 5 + q) * NB + b];
#pragma unroll
    for (int m = 32; m >= 1; m >>= 1) s += __shfl_xor(s, m, 64);
    if (lane == 0) sums[c * 5 + q] = s;
}

// ============================================================
// BN coefficients from double sums (conv layers)
// ============================================================
__global__ __launch_bounds__(64) void k_bn_coef(
                          const double* __restrict__ sums, int C, double invN,
                          const float* __restrict__ grr, const float* __restrict__ gri,
                          const float* __restrict__ gii,
                          const float* __restrict__ ber, const float* __restrict__ bei,
                          float* __restrict__ coef) {
    int c = threadIdx.x;
    if (c >= C) return;
    double sr = sums[c * 5 + 0], si = sums[c * 5 + 1];
    double srr = sums[c * 5 + 2], sii = sums[c * 5 + 3], sri = sums[c * 5 + 4];
    double mr = sr * invN, mi = si * invN;
    double Vrr = srr * invN - mr * mr + EPSV;
    double Vii = sii * invN - mi * mi + EPSV;
    double Vri = sri * invN - mr * mi;
    double s = sqrt(Vrr * Vii - Vri * Vri);
    double t = sqrt(Vrr + Vii + 2.0 * s);
    double inv = 1.0 / (s * t);
    double Rrr = (Vii + s) * inv, Rii = (Vrr + s) * inv, Rri = -Vri * inv;
    double Grr = grr[c], Gri = gri[c], Gii = gii[c];
    double Arr = Grr * Rrr + Gri * Rri, Ari = Grr * Rri + Gri * Rii;
    double Air = Gri * Rrr + Gii * Rri, Aii = Gri * Rri + Gii * Rii;
    coef[c * 6 + 0] = (float)Arr;
    coef[c * 6 + 1] = (float)Ari;
    coef[c * 6 + 2] = (float)Air;
    coef[c * 6 + 3] = (float)Aii;
    coef[c * 6 + 4] = (float)((double)ber[c] - (Arr * mr + Ari * mi));
    coef[c * 6 + 5] = (float)((double)bei[c] - (Air * mr + Aii * mi));
}

// ============================================================
// conv1 recompute + BN affine + relu + mag-pool -> P1 [b][c][56][104]
// grid (728, 10)
// ============================================================
__global__ __launch_bounds__(256) void k_conv1_apply_pool(
                                   const float* __restrict__ xr, const float* __restrict__ xi,
                                   const float* __restrict__ w1r, const float* __restrict__ w1i,
                                   const float* __restrict__ b1r, const float* __restrict__ b1i,
                                   const float* __restrict__ coef,
                                   float* __restrict__ P1r, float* __restrict__ P1i) {
    __shared__ float swr[25], swi[25];
    int tid = threadIdx.x;
    int c = blockIdx.y;
    if (tid < 25) { swr[tid] = w1r[c * 25 + tid]; swi[tid] = w1i[c * 25 + tid]; }
    __syncthreads();
    int idx = blockIdx.x * 256 + tid;
    int pwg = idx % 52;
    int ph  = (idx / 52) % PH1;
    int b   = idx / (52 * PH1);
    int h0 = 2 * ph, w0 = 4 * pwg;
    float br = b1r[c], bi = b1i[c];
    float yr[2][4], yi[2][4];
#pragma unroll
    for (int oi = 0; oi < 2; oi++)
#pragma unroll
        for (int j = 0; j < 4; j++) { yr[oi][j] = br; yi[oi][j] = bi; }
    const float* xrb = xr + b * (H1 * W1);
    const float* xib = xi + b * (H1 * W1);
#pragma unroll
    for (int r = 0; r < 6; r++) {
        float ar[8], ai[8];
        const float* pr = xrb + (h0 + r) * W1 + w0;
        const float* pi = xib + (h0 + r) * W1 + w0;
        *(float4*)&ar[0] = *(const float4*)pr;
        *(float4*)&ar[4] = *(const float4*)(pr + 4);
        *(float4*)&ai[0] = *(const float4*)pi;
        *(float4*)&ai[4] = *(const float4*)(pi + 4);
#pragma unroll
        for (int oi = 0; oi < 2; oi++) {
            int kh = r - oi;
            if (kh >= 0 && kh < 5) {
#pragma unroll
                for (int kw = 0; kw < 5; kw++) {
                    float wrv = swr[kh * 5 + kw], wiv = swi[kh * 5 + kw];
#pragma unroll
                    for (int j = 0; j < 4; j++) {
                        float vr = ar[kw + j], vi = ai[kw + j];
                        yr[oi][j] += vr * wrv - vi * wiv;
                        yi[oi][j] += vr * wiv + vi * wrv;
                    }
                }
            }
        }
    }
    float Arr = coef[c * 6 + 0], Ari = coef[c * 6 + 1];
    float Air = coef[c * 6 + 2], Aii = coef[c * 6 + 3];
    float oR = coef[c * 6 + 4], oI = coef[c * 6 + 5];
    float bm0 = -1.f, br0 = 0.f, bi0 = 0.f;
    float bm1 = -1.f, br1 = 0.f, bi1 = 0.f;
#pragma unroll
    for (int oi = 0; oi < 2; oi++) {
#pragma unroll
        for (int j = 0; j < 4; j++) {
            float rr = fmaxf(Arr * yr[oi][j] + Ari * yi[oi][j] + oR, 0.f);
            float ii = fmaxf(Air * yr[oi][j] + Aii * yi[oi][j] + oI, 0.f);
            float m = rr * rr + ii * ii;
            if (j < 2) { if (m > bm0) { bm0 = m; br0 = rr; bi0 = ii; } }
            else       { if (m > bm1) { bm1 = m; br1 = rr; bi1 = ii; } }
        }
    }
    int pbase = ((b * C1c + c) * PH1 + ph) * PW1 + 2 * pwg;
    *(float2*)&P1r[pbase] = make_float2(br0, br1);
    *(float2*)&P1i[pbase] = make_float2(bi0, bi1);
}

// ============================================================
// conv2: P1 -> buf2 [b][c][52][100] (stored) + stats partials
// grid (10, 325): blockIdx.x = channel-group (FASTEST-varying so the 10
// cg-blocks sharing one P1 slice are dispatched consecutively -> L2 reuse),
// blockIdx.y = pixel block. Round-5 inner body (per-tap LDS broadcast).
// ============================================================
__global__ __launch_bounds__(256) void k_conv2_stats(
                              const float* __restrict__ P1r, const float* __restrict__ P1i,
                              const float* __restrict__ w2r, const float* __restrict__ w2i,
                              const float* __restrict__ b2r, const float* __restrict__ b2i,
                              float* __restrict__ buf2r, float* __restrict__ buf2i,
                              double* __restrict__ part) {
    __shared__ float swr[COG][250], swi[COG][250];
    __shared__ float red[4][5];
    int tid = threadIdx.x;
    int cg = blockIdx.x;                 // couts cg*COG .. cg*COG+COG-1
    int pb = blockIdx.y;                 // pixel block
    if (tid < 250) {
#pragma unroll
        for (int g = 0; g < COG; g++) {
            swr[g][tid] = w2r[(cg * COG + g) * 250 + tid];
            swi[g][tid] = w2i[(cg * COG + g) * 250 + tid];
        }
    }
    __syncthreads();
    int idx = pb * 256 + tid;
    int wg = idx % 25;
    int h  = (idx / 25) % OH2;
    int b  = idx / (25 * OH2);
    int w0 = 4 * wg;
    float yr[COG][4], yi[COG][4];
#pragma unroll
    for (int g = 0; g < COG; g++) {
        float brv = b2r[cg * COG + g], biv = b2i[cg * COG + g];
#pragma unroll
        for (int j = 0; j < 4; j++) { yr[g][j] = brv; yi[g][j] = biv; }
    }
    for (int cin = 0; cin < C1c; cin++) {
        const float* pr = P1r + ((b * C1c + cin) * PH1 + h) * PW1 + w0;
        const float* pi = P1i + ((b * C1c + cin) * PH1 + h) * PW1 + w0;
#pragma unroll
        for (int kh = 0; kh < 5; kh++) {
            float ar[8], ai[8];
            *(float4*)&ar[0] = *(const float4*)(pr + kh * PW1);
            *(float4*)&ar[4] = *(const float4*)(pr + kh * PW1 + 4);
            *(float4*)&ai[0] = *(const float4*)(pi + kh * PW1);
            *(float4*)&ai[4] = *(const float4*)(pi + kh * PW1 + 4);
#pragma unroll
            for (int g = 0; g < COG; g++) {
                const float* wr = &swr[g][cin * 25 + kh * 5];
                const float* wi = &swi[g][cin * 25 + kh * 5];
#pragma unroll
                for (int kw = 0; kw < 5; kw++) {
                    float wrv = wr[kw], wiv = wi[kw];
#pragma unroll
                    for (int j = 0; j < 4; j++) {
                        float vr = ar[kw + j], vi = ai[kw + j];
                        yr[g][j] += vr * wrv - vi * wiv;
                        yi[g][j] += vr * wiv + vi * wrv;
                    }
                }
            }
        }
    }
#pragma unroll
    for (int g = 0; g < COG; g++) {
        int ob = ((b * C2c + cg * COG + g) * OH2 + h) * OW2 + w0;
        *(float4*)&buf2r[ob] = make_float4(yr[g][0], yr[g][1], yr[g][2], yr[g][3]);
        *(float4*)&buf2i[ob] = make_float4(yi[g][0], yi[g][1], yi[g][2], yi[g][3]);
    }
    // stats: f32 per-wave reduce, f64 only at partial write
    for (int g = 0; g < COG; g++) {
        float v[5] = {0.f, 0.f, 0.f, 0.f, 0.f};
#pragma unroll
        for (int j = 0; j < 4; j++) {
            float r = yr[g][j], i = yi[g][j];
            v[0] += r; v[1] += i; v[2] += r * r; v[3] += i * i; v[4] += r * i;
        }
#pragma unroll
        for (int m = 32; m >= 1; m >>= 1) {
#pragma unroll
            for (int q = 0; q < 5; q++) v[q] += __shfl_xor(v[q], m, 64);
        }
        if ((tid & 63) == 0) {
#pragma unroll
            for (int q = 0; q < 5; q++) red[tid >> 6][q] = v[q];
        }
        __syncthreads();
        if (tid == 0) {
            int c = cg * COG + g;
#pragma unroll
            for (int q = 0; q < 5; q++)
                part[(c * 5 + q) * NB2 + pb] =
                    (double)red[0][q] + (double)red[1][q] + (double)red[2][q] + (double)red[3][q];
        }
        __syncthreads();
    }
}

// ============================================================
// BN2 affine + relu + mag-pool, write transposed P2T [k=26000][b=64]
// ============================================================
__global__ __launch_bounds__(256) void k_bn2_pool(
                           const float* __restrict__ buf2r, const float* __restrict__ buf2i,
                           const float* __restrict__ coef,
                           float* __restrict__ P2Tr, float* __restrict__ P2Ti) {
    int idx = blockIdx.x * 256 + threadIdx.x;
    int pw = idx % PW2;
    int ph = (idx / PW2) % PH2;
    int c  = (idx / (PW2 * PH2)) % C2c;
    int b  = idx / (PW2 * PH2 * C2c);
    float Arr = coef[c * 6 + 0], Ari = coef[c * 6 + 1];
    float Air = coef[c * 6 + 2], Aii = coef[c * 6 + 3];
    float oR = coef[c * 6 + 4], oI = coef[c * 6 + 5];
    int ib = ((b * C2c + c) * OH2 + 2 * ph) * OW2 + 2 * pw;
    float rv[4], iv[4];
    rv[0] = buf2r[ib];           iv[0] = buf2i[ib];
    rv[1] = buf2r[ib + 1];       iv[1] = buf2i[ib + 1];
    rv[2] = buf2r[ib + OW2];     iv[2] = buf2i[ib + OW2];
    rv[3] = buf2r[ib + OW2 + 1]; iv[3] = buf2i[ib + OW2 + 1];
    float bm = -1.f, brv = 0.f, biv = 0.f;
#pragma unroll
    for (int q = 0; q < 4; q++) {
        float rr = fmaxf(Arr * rv[q] + Ari * iv[q] + oR, 0.f);
        float ii = fmaxf(Air * rv[q] + Aii * iv[q] + oI, 0.f);
        float m = rr * rr + ii * ii;
        if (m > bm) { bm = m; brv = rr; biv = ii; }
    }
    int k = (c * PH2 + ph) * PW2 + pw;
    P2Tr[k * BB + b] = brv;
    P2Ti[k * BB + b] = biv;
}

// ============================================================
// complex GEMM: out[64][512] += XT[k][64] (x) W[n][k]
// ============================================================
#define GKC 32
__global__ __launch_bounds__(256) void k_gemm_cplx(
                            const float* __restrict__ XTr, const float* __restrict__ XTi,
                            const float* __restrict__ Wr, const float* __restrict__ Wi,
                            float* __restrict__ outR, float* __restrict__ outI,
                            int K, int nStages, int nSplit) {
    __shared__ float lxr[GKC][64], lxi[GKC][64];
    __shared__ float lwr[GKC][68], lwi[GKC][68];
    int tid = threadIdx.x;
    int n0 = blockIdx.x * 64;
    int split = blockIdx.y;
    int bq = tid & 15, nq = tid >> 4;
    int nl = tid & 63, kg = tid >> 6;
    float accR[4][4] = {}, accI[4][4] = {};
    for (int st = split; st < nStages; st += nSplit) {
        int k0 = st * GKC;
        __syncthreads();
#pragma unroll
        for (int u = 0; u < 2; u++) {
            int p = u * 1024 + tid * 4;
            int g = k0 * 64 + p;
            float4 vr = make_float4(0.f, 0.f, 0.f, 0.f), vi = vr;
            if (g < K * 64) {
                vr = *(const float4*)(XTr + g);
                vi = *(const float4*)(XTi + g);
            }
            *(float4*)&((float*)lxr)[p] = vr;
            *(float4*)&((float*)lxi)[p] = vi;
        }
#pragma unroll
        for (int u = 0; u < 2; u++) {
            int koff = kg * 8 + u * 4;
            int k = k0 + koff;
            float4 vr = make_float4(0.f, 0.f, 0.f, 0.f), vi = vr;
            if (k < K) {
                vr = *(const float4*)(Wr + (size_t)(n0 + nl) * K + k);
                vi = *(const float4*)(Wi + (size_t)(n0 + nl) * K + k);
            }
            lwr[koff + 0][nl] = vr.x; lwr[koff + 1][nl] = vr.y;
            lwr[koff + 2][nl] = vr.z; lwr[koff + 3][nl] = vr.w;
            lwi[koff + 0][nl] = vi.x; lwi[koff + 1][nl] = vi.y;
            lwi[koff + 2][nl] = vi.z; lwi[koff + 3][nl] = vi.w;
        }
        __syncthreads();
#pragma unroll 4
        for (int kk = 0; kk < GKC; kk++) {
            float4 xr4 = *(const float4*)&lxr[kk][bq * 4];
            float4 xi4 = *(const float4*)&lxi[kk][bq * 4];
            float4 wr4 = *(const float4*)&lwr[kk][nq * 4];
            float4 wi4 = *(const float4*)&lwi[kk][nq * 4];
            float xra[4] = {xr4.x, xr4.y, xr4.z, xr4.w};
            float xia[4] = {xi4.x, xi4.y, xi4.z, xi4.w};
            float wra[4] = {wr4.x, wr4.y, wr4.z, wr4.w};
            float wia[4] = {wi4.x, wi4.y, wi4.z, wi4.w};
#pragma unroll
            for (int i = 0; i < 4; i++)
#pragma unroll
                for (int j = 0; j < 4; j++) {
                    accR[i][j] += xra[i] * wra[j] - xia[i] * wia[j];
                    accI[i][j] += xra[i] * wia[j] + xia[i] * wra[j];
                }
        }
    }
#pragma unroll
    for (int i = 0; i < 4; i++)
#pragma unroll
        for (int j = 0; j < 4; j++) {
            int b = bq * 4 + i;
            int n = n0 + nq * 4 + j;
            unsafeAtomicAdd(&outR[b * HID + n], accR[i][j]);
            unsafeAtomicAdd(&outI[b * HID + n], accI[i][j]);
        }
}

// ============================================================
// FC BN coef (batch axis only, N=64), C features
// ============================================================
__global__ __launch_bounds__(256) void k_bnfc_coef(
                            const float* __restrict__ inr, const float* __restrict__ ini, int C,
                            const float* __restrict__ grr, const float* __restrict__ gri,
                            const float* __restrict__ gii,
                            const float* __restrict__ ber, const float* __restrict__ bei,
                            float* __restrict__ coef) {
    int f = blockIdx.x * 256 + threadIdx.x;
    if (f >= C) return;
    double sr = 0, si = 0, srr = 0, sii = 0, sri = 0;
    for (int b = 0; b < BB; b++) {
        double r = inr[b * C + f], i = ini[b * C + f];
        sr += r; si += i; srr += r * r; sii += i * i; sri += r * i;
    }
    double invN = 1.0 / BB;
    double mr = sr * invN, mi = si * invN;
    double Vrr = srr * invN - mr * mr + EPSV;
    double Vii = sii * invN - mi * mi + EPSV;
    double Vri = sri * invN - mr * mi;
    double s = sqrt(Vrr * Vii - Vri * Vri);
    double t = sqrt(Vrr + Vii + 2.0 * s);
    double inv = 1.0 / (s * t);
    double Rrr = (Vii + s) * inv, Rii = (Vrr + s) * inv, Rri = -Vri * inv;
    double Grr = grr[f], Gri = gri[f], Gii = gii[f];
    double Arr = Grr * Rrr + Gri * Rri, Ari = Grr * Rri + Gri * Rii;
    double Air = Gri * Rrr + Gii * Rri, Aii = Gri * Rri + Gii * Rii;
    coef[f * 6 + 0] = (float)Arr;
    coef[f * 6 + 1] = (float)Ari;
    coef[f * 6 + 2] = (float)Air;
    coef[f * 6 + 3] = (float)Aii;
    coef[f * 6 + 4] = (float)((double)ber[f] - (Arr * mr + Ari * mi));
    coef[f * 6 + 5] = (float)((double)bei[f] - (Air * mr + Aii * mi));
}

// ============================================================
// FC BN apply + relu; optional transposed output [f][64]
// ============================================================
__global__ __launch_bounds__(256) void k_bnfc_apply(
                             const float* __restrict__ inr, const float* __restrict__ ini,
                             const float* __restrict__ coef,
                             float* __restrict__ outr, float* __restrict__ outi,
                             int C, int transposeOut) {
    int idx = blockIdx.x * 256 + threadIdx.x;
    if (idx >= BB * C) return;
    int f = idx % C;
    int b = idx / C;
    float r = inr[idx], i = ini[idx];
    float rr = fmaxf(coef[f * 6 + 0] * r + coef[f * 6 + 1] * i + coef[f * 6 + 4], 0.f);
    float ii = fmaxf(coef[f * 6 + 2] * r + coef[f * 6 + 3] * i + coef[f * 6 + 5], 0.f);
    if (transposeOut) { outr[f * BB + b] = rr; outi[f * BB + b] = ii; }
    else              { outr[idx] = rr;        outi[idx] = ii; }
}

// ============================================================
// classifier (512->10 complex) + |z|^2 + log_softmax
// ============================================================
__global__ __launch_bounds__(64) void k_classifier(
                             const float* __restrict__ xr, const float* __restrict__ xi,
                             const float* __restrict__ cwr, const float* __restrict__ cwi,
                             const float* __restrict__ cbr, const float* __restrict__ cbi,
                             float* __restrict__ out) {
    int b = blockIdx.x;
    int lane = threadIdx.x;
    __shared__ float z[NCLS];
    for (int cls = 0; cls < NCLS; cls++) {
        float ar = 0.f, ai = 0.f;
#pragma unroll
        for (int j = 0; j < 8; j++) {
            int k = j * 64 + lane;
            float xrv = xr[b * HID + k], xiv = xi[b * HID + k];
            float wr = cwr[cls * HID + k], wi = cwi[cls * HID + k];
            ar += xrv * wr - xiv * wi;
            ai += xrv * wi + xiv * wr;
        }
#pragma unroll
        for (int m = 32; m >= 1; m >>= 1) {
            ar += __shfl_xor(ar, m, 64);
            ai += __shfl_xor(ai, m, 64);
        }
        if (lane == 0) {
            float hr = ar + cbr[cls], hi = ai + cbi[cls];
            z[cls] = hr * hr + hi * hi;
        }
    }
    __syncthreads();
    if (lane == 0) {
        float mx = z[0];
#pragma unroll
        for (int c = 1; c < NCLS; c++) mx = fmaxf(mx, z[c]);
        float s = 0.f;
#pragma unroll
        for (int c = 0; c < NCLS; c++) s += expf(z[c] - mx);
        float ls = logf(s);
#pragma unroll
        for (int c = 0; c < NCLS; c++) out[b * NCLS + c] = z[c] - mx - ls;
    }
}

// ============================================================
extern "C" void kernel_launch(void* const* d_in, const int* in_sizes, int n_in,
                              void* d_out, int out_size, void* d_ws, size_t ws_size,
                              hipStream_t stream) {
    const float* x_re = (const float*)d_in[0];
    const float* x_im = (const float*)d_in[1];
    const float* w1r = (const float*)d_in[2];
    const float* w1i = (const float*)d_in[3];
    const float* b1r = (const float*)d_in[4];
    const float* b1i = (const float*)d_in[5];
    const float* g1rr = (const float*)d_in[6];
    const float* g1ri = (const float*)d_in[7];
    const float* g1ii = (const float*)d_in[8];
    const float* be1r = (const float*)d_in[9];
    const float* be1i = (const float*)d_in[10];
    const float* w2r = (const float*)d_in[11];
    const float* w2i = (const float*)d_in[12];
    const float* b2r = (const float*)d_in[13];
    const float* b2i = (const float*)d_in[14];
    const float* g2rr = (const float*)d_in[15];
    const float* g2ri = (const float*)d_in[16];
    const float* g2ii = (const float*)d_in[17];
    const float* be2r = (const float*)d_in[18];
    const float* be2i = (const float*)d_in[19];
    const float* f1wr = (const float*)d_in[20];
    const float* f1wi = (const float*)d_in[21];
    const float* f1br = (const float*)d_in[22];
    const float* f1bi = (const float*)d_in[23];
    const float* g3rr = (const float*)d_in[24];
    const float* g3ri = (const float*)d_in[25];
    const float* g3ii = (const float*)d_in[26];
    const float* be3r = (const float*)d_in[27];
    const float* be3i = (const float*)d_in[28];
    const float* f2wr = (const float*)d_in[29];
    const float* f2wi = (const float*)d_in[30];
    const float* f2br = (const float*)d_in[31];
    const float* f2bi = (const float*)d_in[32];
    const float* g4rr = (const float*)d_in[33];
    const float* g4ri = (const float*)d_in[34];
    const float* g4ii = (const float*)d_in[35];
    const float* be4r = (const float*)d_in[36];
    const float* be4i = (const float*)d_in[37];
    const float* cwr = (const float*)d_in[38];
    const float* cwi = (const float*)d_in[39];
    const float* cbr = (const float*)d_in[40];
    const float* cbi = (const float*)d_in[41];
    float* out = (float*)d_out;

    char* ws = (char*)d_ws;
    size_t off = 0;
    auto alloc = [&](size_t nbytes) -> void* {
        off = (off + 255) & ~(size_t)255;
        void* p = ws + off;
        off += nbytes;
        return p;
    };
    float* P1r   = (float*)alloc((size_t)BB * C1c * PH1 * PW1 * 4);
    float* P1i   = (float*)alloc((size_t)BB * C1c * PH1 * PW1 * 4);
    float* buf2r = (float*)alloc((size_t)BB * C2c * OH2 * OW2 * 4);
    float* buf2i = (float*)alloc((size_t)BB * C2c * OH2 * OW2 * 4);
    float* P2Tr  = (float*)alloc((size_t)FLAT * BB * 4);
    float* P2Ti  = (float*)alloc((size_t)FLAT * BB * 4);
    float* fc1r  = (float*)alloc((size_t)BB * HID * 4);
    float* fc1i  = (float*)alloc((size_t)BB * HID * 4);
    float* fc1aTr = (float*)alloc((size_t)HID * BB * 4);
    float* fc1aTi = (float*)alloc((size_t)HID * BB * 4);
    float* fc2r  = (float*)alloc((size_t)BB * HID * 4);
    float* fc2i  = (float*)alloc((size_t)BB * HID * 4);
    float* fc2ar = (float*)alloc((size_t)BB * HID * 4);
    float* fc2ai = (float*)alloc((size_t)BB * HID * 4);
    double* part1 = (double*)alloc((size_t)C1c * 5 * NB1 * 8);
    double* part2 = (double*)alloc((size_t)C2c * 5 * NB2 * 8);
    double* sums1 = (double*)alloc(C1c * 5 * 8);
    double* sums2 = (double*)alloc(C2c * 5 * 8);
    float* coef1 = (float*)alloc(C1c * 6 * 4);
    float* coef2 = (float*)alloc(C2c * 6 * 4);
    float* coefF1 = (float*)alloc(HID * 6 * 4);
    float* coefF2 = (float*)alloc(HID * 6 * 4);

    // 0) init
    k_init<<<128, 256, 0, stream>>>(fc1r, fc1i, fc2r, fc2i, f1br, f1bi, f2br, f2bi);
    // 1) conv1 stats partials (8-wide)
    k_conv1_stats<<<dim3(NB1, C1c), 256, 0, stream>>>(x_re, x_im, w1r, w1i, b1r, b1i, part1);
    k_part_reduce<<<C1c, 320, 0, stream>>>(part1, NB1, sums1);
    // 2) BN1 coefs
    k_bn_coef<<<1, 64, 0, stream>>>(sums1, C1c, 1.0 / ((double)BB * OH1 * OW1),
                                    g1rr, g1ri, g1ii, be1r, be1i, coef1);
    // 3) conv1 + BN + relu + pool -> P1
    k_conv1_apply_pool<<<dim3(728, C1c), 256, 0, stream>>>(x_re, x_im, w1r, w1i, b1r, b1i,
                                                           coef1, P1r, P1i);
    // 4) conv2 + store + stats partials (grid: cg fastest for L2 locality)
    k_conv2_stats<<<dim3(C2c / COG, NB2), 256, 0, stream>>>(P1r, P1i, w2r, w2i, b2r, b2i,
                                                            buf2r, buf2i, part2);
    k_part_reduce<<<C2c, 320, 0, stream>>>(part2, NB2, sums2);
    // 5) BN2 coefs
    k_bn_coef<<<1, 64, 0, stream>>>(sums2, C2c, 1.0 / ((double)BB * OH2 * OW2),
                                    g2rr, g2ri, g2ii, be2r, be2i, coef2);
    // 6) BN2 + relu + pool -> P2T [26000][64]
    k_bn2_pool<<<6500, 256, 0, stream>>>(buf2r, buf2i, coef2, P2Tr, P2Ti);
    // 7) FC1 GEMM (K=26000, 813 stages, split 64)
    k_gemm_cplx<<<dim3(8, 64), 256, 0, stream>>>(P2Tr, P2Ti, f1wr, f1wi, fc1r, fc1i,
                                                 FLAT, 813, 64);
    // 8) BN3 coefs
    k_bnfc_coef<<<2, 256, 0, stream>>>(fc1r, fc1i, HID, g3rr, g3ri, g3ii, be3r, be3i, coefF1);
    // 9) BN3 apply + relu -> transposed [512][64]
    k_bnfc_apply<<<128, 256, 0, stream>>>(fc1r, fc1i, coefF1, fc1aTr, fc1aTi, HID, 1);
    // 10) FC2 GEMM (K=512, 16 stages, split 16)
    k_gemm_cplx<<<dim3(8, 16), 256, 0, stream>>>(fc1aTr, fc1aTi, f2wr, f2wi, fc2r, fc2i,
                                                 HID, 16, 16);
    // 11) BN4 coefs
    k_bnfc_coef<<<2, 256, 0, stream>>>(fc2r, fc2i, HID, g4rr, g4ri, g4ii, be4r, be4i, coefF2);
    // 12) BN4 apply + relu -> [64][512]
    k_bnfc_apply<<<128, 256, 0, stream>>>(fc2r, fc2i, coefF2, fc2ar, fc2ai, HID, 0);
    // 13) classifier + log_softmax
    k_classifier<<<64, 64, 0, stream>>>(fc2ar, fc2ai, cwr, cwi, cbr, cbi, out);
}

// Round 9
// 848.596 us; speedup vs baseline: 1.2670x; 1.0854x over previous
//
#include <hip/hip_runtime.h>
#include <math.h>

// ---------------- dims ----------------
#define BB 64
#define H1 116
#define W1 212
#define C1c 10
#define OH1 112
#define OW1 208
#define PH1 56
#define PW1 104
#define C2c 20
#define OH2 52
#define OW2 100
#define PH2 26
#define PW2 50
#define FLAT 26000
#define HID 512
#define NCLS 10
#define EPSV 1e-5
#define NB1 728          // conv1 stats blocks per channel (64*112*26 / 256)
#define NB2 325          // conv2 pixel-blocks (64*52*25 / 256)
#define COG 2            // conv2 output channels per thread
#define FC1SPLIT 128     // FC1 split-K factor (1024 blocks -> 4 waves/SIMD)
// conv2 config ledger (dur): COG=1=362; COG=5=474 (VGPR244); COG=2+2rows+
// scalar-W=504 (SGPR stalls); COG=2+b128-repack=358 (v_mov overhead);
// COG=2+grid-swap+f32-stats=351 (FETCH halved but issue-bound, no win).
// BEST = 315: COG=2, 1 row, per-tap LDS broadcast, pixel-fastest grid,
// f64 stats epilogue. Reverted to exactly that here. Do not "improve" it.

// ============================================================
// init: bias-init FC2 accumulators (FC1 bias folded into reduce)
// ============================================================
__global__ __launch_bounds__(256) void k_init(
                       float* fc2r, float* fc2i,
                       const float* __restrict__ f2br, const float* __restrict__ f2bi) {
    int idx = blockIdx.x * 256 + threadIdx.x;
    if (idx < BB * HID) {
        int n = idx % HID;
        fc2r[idx] = f2br[n]; fc2i[idx] = f2bi[n];
    }
}

// ============================================================
// conv1 + stats partials. grid (728, 10), block 256.
// 8 outputs/thread: 3 aligned float4 window loads per row.
// ============================================================
__global__ __launch_bounds__(256) void k_conv1_stats(
                              const float* __restrict__ xr, const float* __restrict__ xi,
                              const float* __restrict__ w1r, const float* __restrict__ w1i,
                              const float* __restrict__ b1r, const float* __restrict__ b1i,
                              double* __restrict__ part) {
    __shared__ float swr[25], swi[25];
    __shared__ float red[4][5];
    int tid = threadIdx.x;
    int c = blockIdx.y;
    if (tid < 25) { swr[tid] = w1r[c * 25 + tid]; swi[tid] = w1i[c * 25 + tid]; }
    __syncthreads();
    int idx = blockIdx.x * 256 + tid;
    int wg = idx % 26;
    int h  = (idx / 26) % OH1;
    int b  = idx / (26 * OH1);
    int w0 = wg * 8;
    float br = b1r[c], bi = b1i[c];
    float yr[8], yi[8];
#pragma unroll
    for (int j = 0; j < 8; j++) { yr[j] = br; yi[j] = bi; }
    const float* xrb = xr + b * (H1 * W1);
    const float* xib = xi + b * (H1 * W1);
#pragma unroll
    for (int kh = 0; kh < 5; kh++) {
        float ar[12], ai[12];
        const float* pr = xrb + (h + kh) * W1 + w0;
        const float* pi = xib + (h + kh) * W1 + w0;
        *(float4*)&ar[0] = *(const float4*)pr;
        *(float4*)&ar[4] = *(const float4*)(pr + 4);
        *(float4*)&ar[8] = *(const float4*)(pr + 8);
        *(float4*)&ai[0] = *(const float4*)pi;
        *(float4*)&ai[4] = *(const float4*)(pi + 4);
        *(float4*)&ai[8] = *(const float4*)(pi + 8);
#pragma unroll
        for (int kw = 0; kw < 5; kw++) {
            float wrv = swr[kh * 5 + kw], wiv = swi[kh * 5 + kw];
#pragma unroll
            for (int j = 0; j < 8; j++) {
                float vr = ar[kw + j], vi = ai[kw + j];
                yr[j] += vr * wrv - vi * wiv;
                yi[j] += vr * wiv + vi * wrv;
            }
        }
    }
    float v[5] = {0.f, 0.f, 0.f, 0.f, 0.f};
#pragma unroll
    for (int j = 0; j < 8; j++) {
        float r = yr[j], i = yi[j];
        v[0] += r; v[1] += i; v[2] += r * r; v[3] += i * i; v[4] += r * i;
    }
#pragma unroll
    for (int m = 32; m >= 1; m >>= 1) {
#pragma unroll
        for (int q = 0; q < 5; q++) v[q] += __shfl_xor(v[q], m, 64);
    }
    if ((tid & 63) == 0) {
#pragma unroll
        for (int q = 0; q < 5; q++) red[tid >> 6][q] = v[q];
    }
    __syncthreads();
    if (tid == 0) {
#pragma unroll
        for (int q = 0; q < 5; q++)
            part[(c * 5 + q) * NB1 + blockIdx.x] =
                (double)red[0][q] + (double)red[1][q] + (double)red[2][q] + (double)red[3][q];
    }
}

// ============================================================
// reduce per-block partials -> sums[c*5+q]
// ============================================================
__global__ __launch_bounds__(320) void k_part_reduce(
                              const double* __restrict__ part, int NB,
                              double* __restrict__ sums) {
    int c = blockIdx.x;
    int q = threadIdx.x >> 6;
    int lane = threadIdx.x & 63;
    double s = 0.0;
    for (int b = lane; b < NB; b += 64) s += part[(c * 5 + q) * NB + b];
#pragma unroll
    for (int m = 32; m >= 1; m >>= 1) s += __shfl_xor(s, m, 64);
    if (lane == 0) sums[c * 5 + q] = s;
}

// ============================================================
// BN coefficients from double sums (conv layers)
// ============================================================
__global__ __launch_bounds__(64) void k_bn_coef(
                          const double* __restrict__ sums, int C, double invN,
                          const float* __restrict__ grr, const float* __restrict__ gri,
                          const float* __restrict__ gii,
                          const float* __restrict__ ber, const float* __restrict__ bei,
                          float* __restrict__ coef) {
    int c = threadIdx.x;
    if (c >= C) return;
    double sr = sums[c * 5 + 0], si = sums[c * 5 + 1];
    double srr = sums[c * 5 + 2], sii = sums[c * 5 + 3], sri = sums[c * 5 + 4];
    double mr = sr * invN, mi = si * invN;
    double Vrr = srr * invN - mr * mr + EPSV;
    double Vii = sii * invN - mi * mi + EPSV;
    double Vri = sri * invN - mr * mi;
    double s = sqrt(Vrr * Vii - Vri * Vri);
    double t = sqrt(Vrr + Vii + 2.0 * s);
    double inv = 1.0 / (s * t);
    double Rrr = (Vii + s) * inv, Rii = (Vrr + s) * inv, Rri = -Vri * inv;
    double Grr = grr[c], Gri = gri[c], Gii = gii[c];
    double Arr = Grr * Rrr + Gri * Rri, Ari = Grr * Rri + Gri * Rii;
    double Air = Gri * Rrr + Gii * Rri, Aii = Gri * Rri + Gii * Rii;
    coef[c * 6 + 0] = (float)Arr;
    coef[c * 6 + 1] = (float)Ari;
    coef[c * 6 + 2] = (float)Air;
    coef[c * 6 + 3] = (float)Aii;
    coef[c * 6 + 4] = (float)((double)ber[c] - (Arr * mr + Ari * mi));
    coef[c * 6 + 5] = (float)((double)bei[c] - (Air * mr + Aii * mi));
}

// ============================================================
// conv1 recompute + BN affine + relu + mag-pool -> P1 [b][c][56][104]
// grid (728, 10)
// ============================================================
__global__ __launch_bounds__(256) void k_conv1_apply_pool(
                                   const float* __restrict__ xr, const float* __restrict__ xi,
                                   const float* __restrict__ w1r, const float* __restrict__ w1i,
                                   const float* __restrict__ b1r, const float* __restrict__ b1i,
                                   const float* __restrict__ coef,
                                   float* __restrict__ P1r, float* __restrict__ P1i) {
    __shared__ float swr[25], swi[25];
    int tid = threadIdx.x;
    int c = blockIdx.y;
    if (tid < 25) { swr[tid] = w1r[c * 25 + tid]; swi[tid] = w1i[c * 25 + tid]; }
    __syncthreads();
    int idx = blockIdx.x * 256 + tid;
    int pwg = idx % 52;
    int ph  = (idx / 52) % PH1;
    int b   = idx / (52 * PH1);
    int h0 = 2 * ph, w0 = 4 * pwg;
    float br = b1r[c], bi = b1i[c];
    float yr[2][4], yi[2][4];
#pragma unroll
    for (int oi = 0; oi < 2; oi++)
#pragma unroll
        for (int j = 0; j < 4; j++) { yr[oi][j] = br; yi[oi][j] = bi; }
    const float* xrb = xr + b * (H1 * W1);
    const float* xib = xi + b * (H1 * W1);
#pragma unroll
    for (int r = 0; r < 6; r++) {
        float ar[8], ai[8];
        const float* pr = xrb + (h0 + r) * W1 + w0;
        const float* pi = xib + (h0 + r) * W1 + w0;
        *(float4*)&ar[0] = *(const float4*)pr;
        *(float4*)&ar[4] = *(const float4*)(pr + 4);
        *(float4*)&ai[0] = *(const float4*)pi;
        *(float4*)&ai[4] = *(const float4*)(pi + 4);
#pragma unroll
        for (int oi = 0; oi < 2; oi++) {
            int kh = r - oi;
            if (kh >= 0 && kh < 5) {
#pragma unroll
                for (int kw = 0; kw < 5; kw++) {
                    float wrv = swr[kh * 5 + kw], wiv = swi[kh * 5 + kw];
#pragma unroll
                    for (int j = 0; j < 4; j++) {
                        float vr = ar[kw + j], vi = ai[kw + j];
                        yr[oi][j] += vr * wrv - vi * wiv;
                        yi[oi][j] += vr * wiv + vi * wrv;
                    }
                }
            }
        }
    }
    float Arr = coef[c * 6 + 0], Ari = coef[c * 6 + 1];
    float Air = coef[c * 6 + 2], Aii = coef[c * 6 + 3];
    float oR = coef[c * 6 + 4], oI = coef[c * 6 + 5];
    float bm0 = -1.f, br0 = 0.f, bi0 = 0.f;
    float bm1 = -1.f, br1 = 0.f, bi1 = 0.f;
#pragma unroll
    for (int oi = 0; oi < 2; oi++) {
#pragma unroll
        for (int j = 0; j < 4; j++) {
            float rr = fmaxf(Arr * yr[oi][j] + Ari * yi[oi][j] + oR, 0.f);
            float ii = fmaxf(Air * yr[oi][j] + Aii * yi[oi][j] + oI, 0.f);
            float m = rr * rr + ii * ii;
            if (j < 2) { if (m > bm0) { bm0 = m; br0 = rr; bi0 = ii; } }
            else       { if (m > bm1) { bm1 = m; br1 = rr; bi1 = ii; } }
        }
    }
    int pbase = ((b * C1c + c) * PH1 + ph) * PW1 + 2 * pwg;
    *(float2*)&P1r[pbase] = make_float2(br0, br1);
    *(float2*)&P1i[pbase] = make_float2(bi0, bi1);
}

// ============================================================
// conv2: EXACT round-5 (315us) configuration.
// grid (325, 10) pixel-fastest; COG=2 x 4 px; per-tap LDS broadcast;
// f64 stats epilogue.
// ============================================================
__global__ __launch_bounds__(256) void k_conv2_stats(
                              const float* __restrict__ P1r, const float* __restrict__ P1i,
                              const float* __restrict__ w2r, const float* __restrict__ w2i,
                              const float* __restrict__ b2r, const float* __restrict__ b2i,
                              float* __restrict__ buf2r, float* __restrict__ buf2i,
                              double* __restrict__ part) {
    __shared__ float swr[COG][250], swi[COG][250];
    __shared__ double red[4][5];
    int tid = threadIdx.x;
    int cg = blockIdx.y;                 // couts cg*COG .. cg*COG+COG-1
    if (tid < 250) {
#pragma unroll
        for (int g = 0; g < COG; g++) {
            swr[g][tid] = w2r[(cg * COG + g) * 250 + tid];
            swi[g][tid] = w2i[(cg * COG + g) * 250 + tid];
        }
    }
    __syncthreads();
    int idx = blockIdx.x * 256 + tid;
    int wg = idx % 25;
    int h  = (idx / 25) % OH2;
    int b  = idx / (25 * OH2);
    int w0 = 4 * wg;
    float yr[COG][4], yi[COG][4];
#pragma unroll
    for (int g = 0; g < COG; g++) {
        float brv = b2r[cg * COG + g], biv = b2i[cg * COG + g];
#pragma unroll
        for (int j = 0; j < 4; j++) { yr[g][j] = brv; yi[g][j] = biv; }
    }
    for (int cin = 0; cin < C1c; cin++) {
        const float* pr = P1r + ((b * C1c + cin) * PH1 + h) * PW1 + w0;
        const float* pi = P1i + ((b * C1c + cin) * PH1 + h) * PW1 + w0;
#pragma unroll
        for (int kh = 0; kh < 5; kh++) {
            float ar[8], ai[8];
            *(float4*)&ar[0] = *(const float4*)(pr + kh * PW1);
            *(float4*)&ar[4] = *(const float4*)(pr + kh * PW1 + 4);
            *(float4*)&ai[0] = *(const float4*)(pi + kh * PW1);
            *(float4*)&ai[4] = *(const float4*)(pi + kh * PW1 + 4);
#pragma unroll
            for (int g = 0; g < COG; g++) {
                const float* wr = &swr[g][cin * 25 + kh * 5];
                const float* wi = &swi[g][cin * 25 + kh * 5];
#pragma unroll
                for (int kw = 0; kw < 5; kw++) {
                    float wrv = wr[kw], wiv = wi[kw];
#pragma unroll
                    for (int j = 0; j < 4; j++) {
                        float vr = ar[kw + j], vi = ai[kw + j];
                        yr[g][j] += vr * wrv - vi * wiv;
                        yi[g][j] += vr * wiv + vi * wrv;
                    }
                }
            }
        }
    }
#pragma unroll
    for (int g = 0; g < COG; g++) {
        int ob = ((b * C2c + cg * COG + g) * OH2 + h) * OW2 + w0;
        *(float4*)&buf2r[ob] = make_float4(yr[g][0], yr[g][1], yr[g][2], yr[g][3]);
        *(float4*)&buf2i[ob] = make_float4(yi[g][0], yi[g][1], yi[g][2], yi[g][3]);
    }
    for (int g = 0; g < COG; g++) {
        double v[5] = {0, 0, 0, 0, 0};
#pragma unroll
        for (int j = 0; j < 4; j++) {
            double r = yr[g][j], i = yi[g][j];
            v[0] += r; v[1] += i; v[2] += r * r; v[3] += i * i; v[4] += r * i;
        }
#pragma unroll
        for (int m = 32; m >= 1; m >>= 1) {
#pragma unroll
            for (int q = 0; q < 5; q++) v[q] += __shfl_xor(v[q], m, 64);
        }
        if ((tid & 63) == 0) {
#pragma unroll
            for (int q = 0; q < 5; q++) red[tid >> 6][q] = v[q];
        }
        __syncthreads();
        if (tid == 0) {
            int c = cg * COG + g;
#pragma unroll
            for (int q = 0; q < 5; q++)
                part[(c * 5 + q) * NB2 + blockIdx.x] = red[0][q] + red[1][q] + red[2][q] + red[3][q];
        }
        __syncthreads();
    }
}

// ============================================================
// BN2 affine + relu + mag-pool, write transposed P2T [k=26000][b=64]
// ============================================================
__global__ __launch_bounds__(256) void k_bn2_pool(
                           const float* __restrict__ buf2r, const float* __restrict__ buf2i,
                           const float* __restrict__ coef,
                           float* __restrict__ P2Tr, float* __restrict__ P2Ti) {
    int idx = blockIdx.x * 256 + threadIdx.x;
    int pw = idx % PW2;
    int ph = (idx / PW2) % PH2;
    int c  = (idx / (PW2 * PH2)) % C2c;
    int b  = idx / (PW2 * PH2 * C2c);
    float Arr = coef[c * 6 + 0], Ari = coef[c * 6 + 1];
    float Air = coef[c * 6 + 2], Aii = coef[c * 6 + 3];
    float oR = coef[c * 6 + 4], oI = coef[c * 6 + 5];
    int ib = ((b * C2c + c) * OH2 + 2 * ph) * OW2 + 2 * pw;
    float rv[4], iv[4];
    rv[0] = buf2r[ib];           iv[0] = buf2i[ib];
    rv[1] = buf2r[ib + 1];       iv[1] = buf2i[ib + 1];
    rv[2] = buf2r[ib + OW2];     iv[2] = buf2i[ib + OW2];
    rv[3] = buf2r[ib + OW2 + 1]; iv[3] = buf2i[ib + OW2 + 1];
    float bm = -1.f, brv = 0.f, biv = 0.f;
#pragma unroll
    for (int q = 0; q < 4; q++) {
        float rr = fmaxf(Arr * rv[q] + Ari * iv[q] + oR, 0.f);
        float ii = fmaxf(Air * rv[q] + Aii * iv[q] + oI, 0.f);
        float m = rr * rr + ii * ii;
        if (m > bm) { bm = m; brv = rr; biv = ii; }
    }
    int k = (c * PH2 + ph) * PW2 + pw;
    P2Tr[k * BB + b] = brv;
    P2Ti[k * BB + b] = biv;
}

// ============================================================
// complex GEMM, partial-store variant (FC1): each (nblock, split) writes
// its 64x64 tile to part[(split*8 + nblock)*4096 + b*64 + n]. No atomics.
// grid (8, FC1SPLIT) = 1024 blocks -> 4 waves/SIMD.
// ============================================================
#define GKC 32
__global__ __launch_bounds__(256) void k_gemm_cplx_part(
                            const float* __restrict__ XTr, const float* __restrict__ XTi,
                            const float* __restrict__ Wr, const float* __restrict__ Wi,
                            float* __restrict__ partR, float* __restrict__ partI,
                            int K, int nStages, int nSplit) {
    __shared__ float lxr[GKC][64], lxi[GKC][64];
    __shared__ float lwr[GKC][68], lwi[GKC][68];
    int tid = threadIdx.x;
    int n0 = blockIdx.x * 64;
    int split = blockIdx.y;
    int bq = tid & 15, nq = tid >> 4;
    int nl = tid & 63, kg = tid >> 6;
    float accR[4][4] = {}, accI[4][4] = {};
    for (int st = split; st < nStages; st += nSplit) {
        int k0 = st * GKC;
        __syncthreads();
#pragma unroll
        for (int u = 0; u < 2; u++) {
            int p = u * 1024 + tid * 4;
            int g = k0 * 64 + p;
            float4 vr = make_float4(0.f, 0.f, 0.f, 0.f), vi = vr;
            if (g < K * 64) {
                vr = *(const float4*)(XTr + g);
                vi = *(const float4*)(XTi + g);
            }
            *(float4*)&((float*)lxr)[p] = vr;
            *(float4*)&((float*)lxi)[p] = vi;
        }
#pragma unroll
        for (int u = 0; u < 2; u++) {
            int koff = kg * 8 + u * 4;
            int k = k0 + koff;
            float4 vr = make_float4(0.f, 0.f, 0.f, 0.f), vi = vr;
            if (k < K) {
                vr = *(const float4*)(Wr + (size_t)(n0 + nl) * K + k);
                vi = *(const float4*)(Wi + (size_t)(n0 + nl) * K + k);
            }
            lwr[koff + 0][nl] = vr.x; lwr[koff + 1][nl] = vr.y;
            lwr[koff + 2][nl] = vr.z; lwr[koff + 3][nl] = vr.w;
            lwi[koff + 0][nl] = vi.x; lwi[koff + 1][nl] = vi.y;
            lwi[koff + 2][nl] = vi.z; lwi[koff + 3][nl] = vi.w;
        }
        __syncthreads();
#pragma unroll 4
        for (int kk = 0; kk < GKC; kk++) {
            float4 xr4 = *(const float4*)&lxr[kk][bq * 4];
            float4 xi4 = *(const float4*)&lxi[kk][bq * 4];
            float4 wr4 = *(const float4*)&lwr[kk][nq * 4];
            float4 wi4 = *(const float4*)&lwi[kk][nq * 4];
            float xra[4] = {xr4.x, xr4.y, xr4.z, xr4.w};
            float xia[4] = {xi4.x, xi4.y, xi4.z, xi4.w};
            float wra[4] = {wr4.x, wr4.y, wr4.z, wr4.w};
            float wia[4] = {wi4.x, wi4.y, wi4.z, wi4.w};
#pragma unroll
            for (int i = 0; i < 4; i++)
#pragma unroll
                for (int j = 0; j < 4; j++) {
                    accR[i][j] += xra[i] * wra[j] - xia[i] * wia[j];
                    accI[i][j] += xra[i] * wia[j] + xia[i] * wra[j];
                }
        }
    }
    float* bR = partR + ((size_t)(split * 8 + blockIdx.x) << 12);
    float* bI = partI + ((size_t)(split * 8 + blockIdx.x) << 12);
#pragma unroll
    for (int i = 0; i < 4; i++) {
        int row = (bq * 4 + i) * 64 + nq * 4;
        *(float4*)&bR[row] = make_float4(accR[i][0], accR[i][1], accR[i][2], accR[i][3]);
        *(float4*)&bI[row] = make_float4(accI[i][0], accI[i][1], accI[i][2], accI[i][3]);
    }
}

// ============================================================
// FC1 partial reduce: fc1[b][n] = bias[n] + sum_s part[(s*8+nb)*4096 + b*64 + nl]
// grid 128 x 256 (32768 outputs)
// ============================================================
__global__ __launch_bounds__(256) void k_fc1_reduce(
                            const float* __restrict__ partR, const float* __restrict__ partI,
                            const float* __restrict__ f1br, const float* __restrict__ f1bi,
                            float* __restrict__ fc1r, float* __restrict__ fc1i) {
    int idx = blockIdx.x * 256 + threadIdx.x;     // [b][n], n fastest
    int b = idx >> 9, n = idx & 511;
    int nb = n >> 6, nl = n & 63;
    size_t off = ((size_t)nb << 12) + b * 64 + nl;
    float r = f1br[n], i = f1bi[n];
    for (int s = 0; s < FC1SPLIT; s++) {
        r += partR[off + ((size_t)s << 15)];      // s*8*4096
        i += partI[off + ((size_t)s << 15)];
    }
    fc1r[idx] = r;
    fc1i[idx] = i;
}

// ============================================================
// complex GEMM, atomic variant (FC2 — small, low contention)
// ============================================================
__global__ __launch_bounds__(256) void k_gemm_cplx(
                            const float* __restrict__ XTr, const float* __restrict__ XTi,
                            const float* __restrict__ Wr, const float* __restrict__ Wi,
                            float* __restrict__ outR, float* __restrict__ outI,
                            int K, int nStages, int nSplit) {
    __shared__ float lxr[GKC][64], lxi[GKC][64];
    __shared__ float lwr[GKC][68], lwi[GKC][68];
    int tid = threadIdx.x;
    int n0 = blockIdx.x * 64;
    int split = blockIdx.y;
    int bq = tid & 15, nq = tid >> 4;
    int nl = tid & 63, kg = tid >> 6;
    float accR[4][4] = {}, accI[4][4] = {};
    for (int st = split; st < nStages; st += nSplit) {
        int k0 = st * GKC;
        __syncthreads();
#pragma unroll
        for (int u = 0; u < 2; u++) {
            int p = u * 1024 + tid * 4;
            int g = k0 * 64 + p;
            float4 vr = make_float4(0.f, 0.f, 0.f, 0.f), vi = vr;
            if (g < K * 64) {
                vr = *(const float4*)(XTr + g);
                vi = *(const float4*)(XTi + g);
            }
            *(float4*)&((float*)lxr)[p] = vr;
            *(float4*)&((float*)lxi)[p] = vi;
        }
#pragma unroll
        for (int u = 0; u < 2; u++) {
            int koff = kg * 8 + u * 4;
            int k = k0 + koff;
            float4 vr = make_float4(0.f, 0.f, 0.f, 0.f), vi = vr;
            if (k < K) {
                vr = *(const float4*)(Wr + (size_t)(n0 + nl) * K + k);
                vi = *(const float4*)(Wi + (size_t)(n0 + nl) * K + k);
            }
            lwr[koff + 0][nl] = vr.x; lwr[koff + 1][nl] = vr.y;
            lwr[koff + 2][nl] = vr.z; lwr[koff + 3][nl] = vr.w;
            lwi[koff + 0][nl] = vi.x; lwi[koff + 1][nl] = vi.y;
            lwi[koff + 2][nl] = vi.z; lwi[koff + 3][nl] = vi.w;
        }
        __syncthreads();
#pragma unroll 4
        for (int kk = 0; kk < GKC; kk++) {
            float4 xr4 = *(const float4*)&lxr[kk][bq * 4];
            float4 xi4 = *(const float4*)&lxi[kk][bq * 4];
            float4 wr4 = *(const float4*)&lwr[kk][nq * 4];
            float4 wi4 = *(const float4*)&lwi[kk][nq * 4];
            float xra[4] = {xr4.x, xr4.y, xr4.z, xr4.w};
            float xia[4] = {xi4.x, xi4.y, xi4.z, xi4.w};
            float wra[4] = {wr4.x, wr4.y, wr4.z, wr4.w};
            float wia[4] = {wi4.x, wi4.y, wi4.z, wi4.w};
#pragma unroll
            for (int i = 0; i < 4; i++)
#pragma unroll
                for (int j = 0; j < 4; j++) {
                    accR[i][j] += xra[i] * wra[j] - xia[i] * wia[j];
                    accI[i][j] += xra[i] * wia[j] + xia[i] * wra[j];
                }
        }
    }
#pragma unroll
    for (int i = 0; i < 4; i++)
#pragma unroll
        for (int j = 0; j < 4; j++) {
            int b = bq * 4 + i;
            int n = n0 + nq * 4 + j;
            unsafeAtomicAdd(&outR[b * HID + n], accR[i][j]);
            unsafeAtomicAdd(&outI[b * HID + n], accI[i][j]);
        }
}

// ============================================================
// FC BN coef (batch axis only, N=64), C features
// ============================================================
__global__ __launch_bounds__(256) void k_bnfc_coef(
                            const float* __restrict__ inr, const float* __restrict__ ini, int C,
                            const float* __restrict__ grr, const float* __restrict__ gri,
                            const float* __restrict__ gii,
                            const float* __restrict__ ber, const float* __restrict__ bei,
                            float* __restrict__ coef) {
    int f = blockIdx.x * 256 + threadIdx.x;
    if (f >= C) return;
    double sr = 0, si = 0, srr = 0, sii = 0, sri = 0;
    for (int b = 0; b < BB; b++) {
        double r = inr[b * C + f], i = ini[b * C + f];
        sr += r; si += i; srr += r * r; sii += i * i; sri += r * i;
    }
    double invN = 1.0 / BB;
    double mr = sr * invN, mi = si * invN;
    double Vrr = srr * invN - mr * mr + EPSV;
    double Vii = sii * invN - mi * mi + EPSV;
    double Vri = sri * invN - mr * mi;
    double s = sqrt(Vrr * Vii - Vri * Vri);
    double t = sqrt(Vrr + Vii + 2.0 * s);
    double inv = 1.0 / (s * t);
    double Rrr = (Vii + s) * inv, Rii = (Vrr + s) * inv, Rri = -Vri * inv;
    double Grr = grr[f], Gri = gri[f], Gii = gii[f];
    double Arr = Grr * Rrr + Gri * Rri, Ari = Grr * Rri + Gri * Rii;
    double Air = Gri * Rrr + Gii * Rri, Aii = Gri * Rri + Gii * Rii;
    coef[f * 6 + 0] = (float)Arr;
    coef[f * 6 + 1] = (float)Ari;
    coef[f * 6 + 2] = (float)Air;
    coef[f * 6 + 3] = (float)Aii;
    coef[f * 6 + 4] = (float)((double)ber[f] - (Arr * mr + Ari * mi));
    coef[f * 6 + 5] = (float)((double)bei[f] - (Air * mr + Aii * mi));
}

// ============================================================
// FC BN apply + relu; optional transposed output [f][64]
// ============================================================
__global__ __launch_bounds__(256) void k_bnfc_apply(
                             const float* __restrict__ inr, const float* __restrict__ ini,
                             const float* __restrict__ coef,
                             float* __restrict__ outr, float* __restrict__ outi,
                             int C, int transposeOut) {
    int idx = blockIdx.x * 256 + threadIdx.x;
    if (idx >= BB * C) return;
    int f = idx % C;
    int b = idx / C;
    float r = inr[idx], i = ini[idx];
    float rr = fmaxf(coef[f * 6 + 0] * r + coef[f * 6 + 1] * i + coef[f * 6 + 4], 0.f);
    float ii = fmaxf(coef[f * 6 + 2] * r + coef[f * 6 + 3] * i + coef[f * 6 + 5], 0.f);
    if (transposeOut) { outr[f * BB + b] = rr; outi[f * BB + b] = ii; }
    else              { outr[idx] = rr;        outi[idx] = ii; }
}

// ============================================================
// classifier (512->10 complex) + |z|^2 + log_softmax
// ============================================================
__global__ __launch_bounds__(64) void k_classifier(
                             const float* __restrict__ xr, const float* __restrict__ xi,
                             const float* __restrict__ cwr, const float* __restrict__ cwi,
                             const float* __restrict__ cbr, const float* __restrict__ cbi,
                             float* __restrict__ out) {
    int b = blockIdx.x;
    int lane = threadIdx.x;
    __shared__ float z[NCLS];
    for (int cls = 0; cls < NCLS; cls++) {
        float ar = 0.f, ai = 0.f;
#pragma unroll
        for (int j = 0; j < 8; j++) {
            int k = j * 64 + lane;
            float xrv = xr[b * HID + k], xiv = xi[b * HID + k];
            float wr = cwr[cls * HID + k], wi = cwi[cls * HID + k];
            ar += xrv * wr - xiv * wi;
            ai += xrv * wi + xiv * wr;
        }
#pragma unroll
        for (int m = 32; m >= 1; m >>= 1) {
            ar += __shfl_xor(ar, m, 64);
            ai += __shfl_xor(ai, m, 64);
        }
        if (lane == 0) {
            float hr = ar + cbr[cls], hi = ai + cbi[cls];
            z[cls] = hr * hr + hi * hi;
        }
    }
    __syncthreads();
    if (lane == 0) {
        float mx = z[0];
#pragma unroll
        for (int c = 1; c < NCLS; c++) mx = fmaxf(mx, z[c]);
        float s = 0.f;
#pragma unroll
        for (int c = 0; c < NCLS; c++) s += expf(z[c] - mx);
        float ls = logf(s);
#pragma unroll
        for (int c = 0; c < NCLS; c++) out[b * NCLS + c] = z[c] - mx - ls;
    }
}

// ============================================================
extern "C" void kernel_launch(void* const* d_in, const int* in_sizes, int n_in,
                              void* d_out, int out_size, void* d_ws, size_t ws_size,
                              hipStream_t stream) {
    const float* x_re = (const float*)d_in[0];
    const float* x_im = (const float*)d_in[1];
    const float* w1r = (const float*)d_in[2];
    const float* w1i = (const float*)d_in[3];
    const float* b1r = (const float*)d_in[4];
    const float* b1i = (const float*)d_in[5];
    const float* g1rr = (const float*)d_in[6];
    const float* g1ri = (const float*)d_in[7];
    const float* g1ii = (const float*)d_in[8];
    const float* be1r = (const float*)d_in[9];
    const float* be1i = (const float*)d_in[10];
    const float* w2r = (const float*)d_in[11];
    const float* w2i = (const float*)d_in[12];
    const float* b2r = (const float*)d_in[13];
    const float* b2i = (const float*)d_in[14];
    const float* g2rr = (const float*)d_in[15];
    const float* g2ri = (const float*)d_in[16];
    const float* g2ii = (const float*)d_in[17];
    const float* be2r = (const float*)d_in[18];
    const float* be2i = (const float*)d_in[19];
    const float* f1wr = (const float*)d_in[20];
    const float* f1wi = (const float*)d_in[21];
    const float* f1br = (const float*)d_in[22];
    const float* f1bi = (const float*)d_in[23];
    const float* g3rr = (const float*)d_in[24];
    const float* g3ri = (const float*)d_in[25];
    const float* g3ii = (const float*)d_in[26];
    const float* be3r = (const float*)d_in[27];
    const float* be3i = (const float*)d_in[28];
    const float* f2wr = (const float*)d_in[29];
    const float* f2wi = (const float*)d_in[30];
    const float* f2br = (const float*)d_in[31];
    const float* f2bi = (const float*)d_in[32];
    const float* g4rr = (const float*)d_in[33];
    const float* g4ri = (const float*)d_in[34];
    const float* g4ii = (const float*)d_in[35];
    const float* be4r = (const float*)d_in[36];
    const float* be4i = (const float*)d_in[37];
    const float* cwr = (const float*)d_in[38];
    const float* cwi = (const float*)d_in[39];
    const float* cbr = (const float*)d_in[40];
    const float* cbi = (const float*)d_in[41];
    float* out = (float*)d_out;

    char* ws = (char*)d_ws;
    size_t off = 0;
    auto alloc = [&](size_t nbytes) -> void* {
        off = (off + 255) & ~(size_t)255;
        void* p = ws + off;
        off += nbytes;
        return p;
    };
    float* P1r   = (float*)alloc((size_t)BB * C1c * PH1 * PW1 * 4);
    float* P1i   = (float*)alloc((size_t)BB * C1c * PH1 * PW1 * 4);
    float* buf2r = (float*)alloc((size_t)BB * C2c * OH2 * OW2 * 4);   // 26.6 MB
    float* buf2i = (float*)alloc((size_t)BB * C2c * OH2 * OW2 * 4);   // 26.6 MB
    float* P2Tr  = (float*)alloc((size_t)FLAT * BB * 4);
    float* P2Ti  = (float*)alloc((size_t)FLAT * BB * 4);
    float* fc1r  = (float*)alloc((size_t)BB * HID * 4);
    float* fc1i  = (float*)alloc((size_t)BB * HID * 4);
    float* fc1aTr = (float*)alloc((size_t)HID * BB * 4);
    float* fc1aTi = (float*)alloc((size_t)HID * BB * 4);
    float* fc2r  = (float*)alloc((size_t)BB * HID * 4);
    float* fc2i  = (float*)alloc((size_t)BB * HID * 4);
    float* fc2ar = (float*)alloc((size_t)BB * HID * 4);
    float* fc2ai = (float*)alloc((size_t)BB * HID * 4);
    double* part1 = (double*)alloc((size_t)C1c * 5 * NB1 * 8);
    double* part2 = (double*)alloc((size_t)C2c * 5 * NB2 * 8);
    double* sums1 = (double*)alloc(C1c * 5 * 8);
    double* sums2 = (double*)alloc(C2c * 5 * 8);
    float* coef1 = (float*)alloc(C1c * 6 * 4);
    float* coef2 = (float*)alloc(C2c * 6 * 4);
    float* coefF1 = (float*)alloc(HID * 6 * 4);
    float* coefF2 = (float*)alloc(HID * 6 * 4);
    // FC1 partials alias buf2 (dead after k_bn2_pool; FC1SPLIT*8*4096*4 =
    // 16.8 MB each, fits inside each 26.6 MB buf2 half)
    float* gpR = buf2r;
    float* gpI = buf2i;

    // 0) init (fc2 bias only; fc1 bias folded into k_fc1_reduce)
    k_init<<<128, 256, 0, stream>>>(fc2r, fc2i, f2br, f2bi);
    // 1) conv1 stats partials (8-wide)
    k_conv1_stats<<<dim3(NB1, C1c), 256, 0, stream>>>(x_re, x_im, w1r, w1i, b1r, b1i, part1);
    k_part_reduce<<<C1c, 320, 0, stream>>>(part1, NB1, sums1);
    // 2) BN1 coefs
    k_bn_coef<<<1, 64, 0, stream>>>(sums1, C1c, 1.0 / ((double)BB * OH1 * OW1),
                                    g1rr, g1ri, g1ii, be1r, be1i, coef1);
    // 3) conv1 + BN + relu + pool -> P1
    k_conv1_apply_pool<<<dim3(728, C1c), 256, 0, stream>>>(x_re, x_im, w1r, w1i, b1r, b1i,
                                                           coef1, P1r, P1i);
    // 4) conv2 + store + stats partials (round-5 config, grid (325,10))
    k_conv2_stats<<<dim3(NB2, C2c / COG), 256, 0, stream>>>(P1r, P1i, w2r, w2i, b2r, b2i,
                                                            buf2r, buf2i, part2);
    k_part_reduce<<<C2c, 320, 0, stream>>>(part2, NB2, sums2);
    // 5) BN2 coefs
    k_bn_coef<<<1, 64, 0, stream>>>(sums2, C2c, 1.0 / ((double)BB * OH2 * OW2),
                                    g2rr, g2ri, g2ii, be2r, be2i, coef2);
    // 6) BN2 + relu + pool -> P2T [26000][64]  (last reader of buf2)
    k_bn2_pool<<<6500, 256, 0, stream>>>(buf2r, buf2i, coef2, P2Tr, P2Ti);
    // 7) FC1 GEMM: split-K 128, partial tiles into gp (aliases buf2), then reduce
    k_gemm_cplx_part<<<dim3(8, FC1SPLIT), 256, 0, stream>>>(P2Tr, P2Ti, f1wr, f1wi,
                                                            gpR, gpI, FLAT, 813, FC1SPLIT);
    k_fc1_reduce<<<128, 256, 0, stream>>>(gpR, gpI, f1br, f1bi, fc1r, fc1i);
    // 8) BN3 coefs
    k_bnfc_coef<<<2, 256, 0, stream>>>(fc1r, fc1i, HID, g3rr, g3ri, g3ii, be3r, be3i, coefF1);
    // 9) BN3 apply + relu -> transposed [512][64]
    k_bnfc_apply<<<128, 256, 0, stream>>>(fc1r, fc1i, coefF1, fc1aTr, fc1aTi, HID, 1);
    // 10) FC2 GEMM (K=512, 16 stages, split 16, atomic variant)
    k_gemm_cplx<<<dim3(8, 16), 256, 0, stream>>>(fc1aTr, fc1aTi, f2wr, f2wi, fc2r, fc2i,
                                                 HID, 16, 16);
    // 11) BN4 coefs
    k_bnfc_coef<<<2, 256, 0, stream>>>(fc2r, fc2i, HID, g4rr, g4ri, g4ii, be4r, be4i, coefF2);
    // 12) BN4 apply + relu -> [64][512]
    k_bnfc_apply<<<128, 256, 0, stream>>>(fc2r, fc2i, coefF2, fc2ar, fc2ai, HID, 0);
    // 13) classifier + log_softmax
    k_classifier<<<64, 64, 0, stream>>>(fc2ar, fc2ai, cwr, cwi, cbr, cbi, out);
}

// Round 10
// 694.606 us; speedup vs baseline: 1.5479x; 1.2217x over previous
//
#include <hip/hip_runtime.h>
#include <math.h>

// ---------------- dims ----------------
#define BB 64
#define H1 116
#define W1 212
#define C1c 10
#define OH1 112
#define OW1 208
#define PH1 56
#define PW1 104
#define C2c 20
#define OH2 52
#define OW2 100
#define PH2 26
#define PW2 50
#define FLAT 26000
#define HID 512
#define NCLS 10
#define EPSV 1e-5
#define NB1 728          // conv1 stats blocks per channel (64*112*26 / 256)
#define NB2 325          // conv2 pixel-blocks (64*52*25 / 256)
#define COG 2            // conv2 output channels per thread
#define FC1SPLIT 128     // FC1 split-K factor (1024 blocks -> 4 waves/SIMD)
// conv2 config ledger (dur): COG=1=362; COG=5=474 (VGPR244); COG=2+2rows+
// scalar-W=504 (SGPR stalls); COG=2+b128-repack=358 (v_mov overhead);
// COG=2+grid-swap+f32-stats=351. BEST=315: COG=2, 1 row, per-tap LDS
// broadcast, pixel-fastest grid, f64 stats epilogue.
// R10 change: `y += a*b - c*d` compiles to mul+fma+add (no reassociation
// across +=). Hand-written fmaf chains give the 2-FMA form everywhere.

// complex MAC: (yr,yi) += (vr+ivi)*(wr+iwi) as 4 fmaf
#define CMAC(yr, yi, vr, vi, wrv, wiv)            \
    do {                                          \
        (yr) = fmaf((vr), (wrv), (yr));           \
        (yr) = fmaf(-(vi), (wiv), (yr));          \
        (yi) = fmaf((vr), (wiv), (yi));           \
        (yi) = fmaf((vi), (wrv), (yi));           \
    } while (0)

// ============================================================
// init: bias-init FC2 accumulators (FC1 bias folded into reduce)
// ============================================================
__global__ __launch_bounds__(256) void k_init(
                       float* fc2r, float* fc2i,
                       const float* __restrict__ f2br, const float* __restrict__ f2bi) {
    int idx = blockIdx.x * 256 + threadIdx.x;
    if (idx < BB * HID) {
        int n = idx % HID;
        fc2r[idx] = f2br[n]; fc2i[idx] = f2bi[n];
    }
}

// ============================================================
// conv1 + stats partials. grid (728, 10), block 256. 8 outputs/thread.
// ============================================================
__global__ __launch_bounds__(256) void k_conv1_stats(
                              const float* __restrict__ xr, const float* __restrict__ xi,
                              const float* __restrict__ w1r, const float* __restrict__ w1i,
                              const float* __restrict__ b1r, const float* __restrict__ b1i,
                              double* __restrict__ part) {
    __shared__ float swr[25], swi[25];
    __shared__ float red[4][5];
    int tid = threadIdx.x;
    int c = blockIdx.y;
    if (tid < 25) { swr[tid] = w1r[c * 25 + tid]; swi[tid] = w1i[c * 25 + tid]; }
    __syncthreads();
    int idx = blockIdx.x * 256 + tid;
    int wg = idx % 26;
    int h  = (idx / 26) % OH1;
    int b  = idx / (26 * OH1);
    int w0 = wg * 8;
    float br = b1r[c], bi = b1i[c];
    float yr[8], yi[8];
#pragma unroll
    for (int j = 0; j < 8; j++) { yr[j] = br; yi[j] = bi; }
    const float* xrb = xr + b * (H1 * W1);
    const float* xib = xi + b * (H1 * W1);
#pragma unroll
    for (int kh = 0; kh < 5; kh++) {
        float ar[12], ai[12];
        const float* pr = xrb + (h + kh) * W1 + w0;
        const float* pi = xib + (h + kh) * W1 + w0;
        *(float4*)&ar[0] = *(const float4*)pr;
        *(float4*)&ar[4] = *(const float4*)(pr + 4);
        *(float4*)&ar[8] = *(const float4*)(pr + 8);
        *(float4*)&ai[0] = *(const float4*)pi;
        *(float4*)&ai[4] = *(const float4*)(pi + 4);
        *(float4*)&ai[8] = *(const float4*)(pi + 8);
#pragma unroll
        for (int kw = 0; kw < 5; kw++) {
            float wrv = swr[kh * 5 + kw], wiv = swi[kh * 5 + kw];
#pragma unroll
            for (int j = 0; j < 8; j++) {
                CMAC(yr[j], yi[j], ar[kw + j], ai[kw + j], wrv, wiv);
            }
        }
    }
    float v[5] = {0.f, 0.f, 0.f, 0.f, 0.f};
#pragma unroll
    for (int j = 0; j < 8; j++) {
        float r = yr[j], i = yi[j];
        v[0] += r; v[1] += i;
        v[2] = fmaf(r, r, v[2]); v[3] = fmaf(i, i, v[3]); v[4] = fmaf(r, i, v[4]);
    }
#pragma unroll
    for (int m = 32; m >= 1; m >>= 1) {
#pragma unroll
        for (int q = 0; q < 5; q++) v[q] += __shfl_xor(v[q], m, 64);
    }
    if ((tid & 63) == 0) {
#pragma unroll
        for (int q = 0; q < 5; q++) red[tid >> 6][q] = v[q];
    }
    __syncthreads();
    if (tid == 0) {
#pragma unroll
        for (int q = 0; q < 5; q++)
            part[(c * 5 + q) * NB1 + blockIdx.x] =
                (double)red[0][q] + (double)red[1][q] + (double)red[2][q] + (double)red[3][q];
    }
}

// ============================================================
// reduce per-block partials -> sums[c*5+q]
// ============================================================
__global__ __launch_bounds__(320) void k_part_reduce(
                              const double* __restrict__ part, int NB,
                              double* __restrict__ sums) {
    int c = blockIdx.x;
    int q = threadIdx.x >> 6;
    int lane = threadIdx.x & 63;
    double s = 0.0;
    for (int b = lane; b < NB; b += 64) s += part[(c * 5 + q) * NB + b];
#pragma unroll
    for (int m = 32; m >= 1; m >>= 1) s += __shfl_xor(s, m, 64);
    if (lane == 0) sums[c * 5 + q] = s;
}

// ============================================================
// BN coefficients from double sums (conv layers)
// ============================================================
__global__ __launch_bounds__(64) void k_bn_coef(
                          const double* __restrict__ sums, int C, double invN,
                          const float* __restrict__ grr, const float* __restrict__ gri,
                          const float* __restrict__ gii,
                          const float* __restrict__ ber, const float* __restrict__ bei,
                          float* __restrict__ coef) {
    int c = threadIdx.x;
    if (c >= C) return;
    double sr = sums[c * 5 + 0], si = sums[c * 5 + 1];
    double srr = sums[c * 5 + 2], sii = sums[c * 5 + 3], sri = sums[c * 5 + 4];
    double mr = sr * invN, mi = si * invN;
    double Vrr = srr * invN - mr * mr + EPSV;
    double Vii = sii * invN - mi * mi + EPSV;
    double Vri = sri * invN - mr * mi;
    double s = sqrt(Vrr * Vii - Vri * Vri);
    double t = sqrt(Vrr + Vii + 2.0 * s);
    double inv = 1.0 / (s * t);
    double Rrr = (Vii + s) * inv, Rii = (Vrr + s) * inv, Rri = -Vri * inv;
    double Grr = grr[c], Gri = gri[c], Gii = gii[c];
    double Arr = Grr * Rrr + Gri * Rri, Ari = Grr * Rri + Gri * Rii;
    double Air = Gri * Rrr + Gii * Rri, Aii = Gri * Rri + Gii * Rii;
    coef[c * 6 + 0] = (float)Arr;
    coef[c * 6 + 1] = (float)Ari;
    coef[c * 6 + 2] = (float)Air;
    coef[c * 6 + 3] = (float)Aii;
    coef[c * 6 + 4] = (float)((double)ber[c] - (Arr * mr + Ari * mi));
    coef[c * 6 + 5] = (float)((double)bei[c] - (Air * mr + Aii * mi));
}

// ============================================================
// conv1 recompute + BN affine + relu + mag-pool -> P1 [b][c][56][104]
// grid (728, 10)
// ============================================================
__global__ __launch_bounds__(256) void k_conv1_apply_pool(
                                   const float* __restrict__ xr, const float* __restrict__ xi,
                                   const float* __restrict__ w1r, const float* __restrict__ w1i,
                                   const float* __restrict__ b1r, const float* __restrict__ b1i,
                                   const float* __restrict__ coef,
                                   float* __restrict__ P1r, float* __restrict__ P1i) {
    __shared__ float swr[25], swi[25];
    int tid = threadIdx.x;
    int c = blockIdx.y;
    if (tid < 25) { swr[tid] = w1r[c * 25 + tid]; swi[tid] = w1i[c * 25 + tid]; }
    __syncthreads();
    int idx = blockIdx.x * 256 + tid;
    int pwg = idx % 52;
    int ph  = (idx / 52) % PH1;
    int b   = idx / (52 * PH1);
    int h0 = 2 * ph, w0 = 4 * pwg;
    float br = b1r[c], bi = b1i[c];
    float yr[2][4], yi[2][4];
#pragma unroll
    for (int oi = 0; oi < 2; oi++)
#pragma unroll
        for (int j = 0; j < 4; j++) { yr[oi][j] = br; yi[oi][j] = bi; }
    const float* xrb = xr + b * (H1 * W1);
    const float* xib = xi + b * (H1 * W1);
#pragma unroll
    for (int r = 0; r < 6; r++) {
        float ar[8], ai[8];
        const float* pr = xrb + (h0 + r) * W1 + w0;
        const float* pi = xib + (h0 + r) * W1 + w0;
        *(float4*)&ar[0] = *(const float4*)pr;
        *(float4*)&ar[4] = *(const float4*)(pr + 4);
        *(float4*)&ai[0] = *(const float4*)pi;
        *(float4*)&ai[4] = *(const float4*)(pi + 4);
#pragma unroll
        for (int oi = 0; oi < 2; oi++) {
            int kh = r - oi;
            if (kh >= 0 && kh < 5) {
#pragma unroll
                for (int kw = 0; kw < 5; kw++) {
                    float wrv = swr[kh * 5 + kw], wiv = swi[kh * 5 + kw];
#pragma unroll
                    for (int j = 0; j < 4; j++) {
                        CMAC(yr[oi][j], yi[oi][j], ar[kw + j], ai[kw + j], wrv, wiv);
                    }
                }
            }
        }
    }
    float Arr = coef[c * 6 + 0], Ari = coef[c * 6 + 1];
    float Air = coef[c * 6 + 2], Aii = coef[c * 6 + 3];
    float oR = coef[c * 6 + 4], oI = coef[c * 6 + 5];
    float bm0 = -1.f, br0 = 0.f, bi0 = 0.f;
    float bm1 = -1.f, br1 = 0.f, bi1 = 0.f;
#pragma unroll
    for (int oi = 0; oi < 2; oi++) {
#pragma unroll
        for (int j = 0; j < 4; j++) {
            float rr = fmaxf(Arr * yr[oi][j] + Ari * yi[oi][j] + oR, 0.f);
            float ii = fmaxf(Air * yr[oi][j] + Aii * yi[oi][j] + oI, 0.f);
            float m = fmaf(rr, rr, ii * ii);
            if (j < 2) { if (m > bm0) { bm0 = m; br0 = rr; bi0 = ii; } }
            else       { if (m > bm1) { bm1 = m; br1 = rr; bi1 = ii; } }
        }
    }
    int pbase = ((b * C1c + c) * PH1 + ph) * PW1 + 2 * pwg;
    *(float2*)&P1r[pbase] = make_float2(br0, br1);
    *(float2*)&P1i[pbase] = make_float2(bi0, bi1);
}

// ============================================================
// conv2: round-5 structure + fmaf chains.
// grid (325, 10) pixel-fastest; COG=2 x 4 px; per-tap LDS broadcast;
// f64 stats epilogue.
// ============================================================
__global__ __launch_bounds__(256) void k_conv2_stats(
                              const float* __restrict__ P1r, const float* __restrict__ P1i,
                              const float* __restrict__ w2r, const float* __restrict__ w2i,
                              const float* __restrict__ b2r, const float* __restrict__ b2i,
                              float* __restrict__ buf2r, float* __restrict__ buf2i,
                              double* __restrict__ part) {
    __shared__ float swr[COG][250], swi[COG][250];
    __shared__ double red[4][5];
    int tid = threadIdx.x;
    int cg = blockIdx.y;                 // couts cg*COG .. cg*COG+COG-1
    if (tid < 250) {
#pragma unroll
        for (int g = 0; g < COG; g++) {
            swr[g][tid] = w2r[(cg * COG + g) * 250 + tid];
            swi[g][tid] = w2i[(cg * COG + g) * 250 + tid];
        }
    }
    __syncthreads();
    int idx = blockIdx.x * 256 + tid;
    int wg = idx % 25;
    int h  = (idx / 25) % OH2;
    int b  = idx / (25 * OH2);
    int w0 = 4 * wg;
    float yr[COG][4], yi[COG][4];
#pragma unroll
    for (int g = 0; g < COG; g++) {
        float brv = b2r[cg * COG + g], biv = b2i[cg * COG + g];
#pragma unroll
        for (int j = 0; j < 4; j++) { yr[g][j] = brv; yi[g][j] = biv; }
    }
    for (int cin = 0; cin < C1c; cin++) {
        const float* pr = P1r + ((b * C1c + cin) * PH1 + h) * PW1 + w0;
        const float* pi = P1i + ((b * C1c + cin) * PH1 + h) * PW1 + w0;
#pragma unroll
        for (int kh = 0; kh < 5; kh++) {
            float ar[8], ai[8];
            *(float4*)&ar[0] = *(const float4*)(pr + kh * PW1);
            *(float4*)&ar[4] = *(const float4*)(pr + kh * PW1 + 4);
            *(float4*)&ai[0] = *(const float4*)(pi + kh * PW1);
            *(float4*)&ai[4] = *(const float4*)(pi + kh * PW1 + 4);
#pragma unroll
            for (int g = 0; g < COG; g++) {
                const float* wr = &swr[g][cin * 25 + kh * 5];
                const float* wi = &swi[g][cin * 25 + kh * 5];
#pragma unroll
                for (int kw = 0; kw < 5; kw++) {
                    float wrv = wr[kw], wiv = wi[kw];
#pragma unroll
                    for (int j = 0; j < 4; j++) {
                        CMAC(yr[g][j], yi[g][j], ar[kw + j], ai[kw + j], wrv, wiv);
                    }
                }
            }
        }
    }
#pragma unroll
    for (int g = 0; g < COG; g++) {
        int ob = ((b * C2c + cg * COG + g) * OH2 + h) * OW2 + w0;
        *(float4*)&buf2r[ob] = make_float4(yr[g][0], yr[g][1], yr[g][2], yr[g][3]);
        *(float4*)&buf2i[ob] = make_float4(yi[g][0], yi[g][1], yi[g][2], yi[g][3]);
    }
    for (int g = 0; g < COG; g++) {
        double v[5] = {0, 0, 0, 0, 0};
#pragma unroll
        for (int j = 0; j < 4; j++) {
            double r = yr[g][j], i = yi[g][j];
            v[0] += r; v[1] += i; v[2] += r * r; v[3] += i * i; v[4] += r * i;
        }
#pragma unroll
        for (int m = 32; m >= 1; m >>= 1) {
#pragma unroll
            for (int q = 0; q < 5; q++) v[q] += __shfl_xor(v[q], m, 64);
        }
        if ((tid & 63) == 0) {
#pragma unroll
            for (int q = 0; q < 5; q++) red[tid >> 6][q] = v[q];
        }
        __syncthreads();
        if (tid == 0) {
            int c = cg * COG + g;
#pragma unroll
            for (int q = 0; q < 5; q++)
                part[(c * 5 + q) * NB2 + blockIdx.x] = red[0][q] + red[1][q] + red[2][q] + red[3][q];
        }
        __syncthreads();
    }
}

// ============================================================
// BN2 affine + relu + mag-pool, write transposed P2T [k=26000][b=64]
// ============================================================
__global__ __launch_bounds__(256) void k_bn2_pool(
                           const float* __restrict__ buf2r, const float* __restrict__ buf2i,
                           const float* __restrict__ coef,
                           float* __restrict__ P2Tr, float* __restrict__ P2Ti) {
    int idx = blockIdx.x * 256 + threadIdx.x;
    int pw = idx % PW2;
    int ph = (idx / PW2) % PH2;
    int c  = (idx / (PW2 * PH2)) % C2c;
    int b  = idx / (PW2 * PH2 * C2c);
    float Arr = coef[c * 6 + 0], Ari = coef[c * 6 + 1];
    float Air = coef[c * 6 + 2], Aii = coef[c * 6 + 3];
    float oR = coef[c * 6 + 4], oI = coef[c * 6 + 5];
    int ib = ((b * C2c + c) * OH2 + 2 * ph) * OW2 + 2 * pw;
    float rv[4], iv[4];
    rv[0] = buf2r[ib];           iv[0] = buf2i[ib];
    rv[1] = buf2r[ib + 1];       iv[1] = buf2i[ib + 1];
    rv[2] = buf2r[ib + OW2];     iv[2] = buf2i[ib + OW2];
    rv[3] = buf2r[ib + OW2 + 1]; iv[3] = buf2i[ib + OW2 + 1];
    float bm = -1.f, brv = 0.f, biv = 0.f;
#pragma unroll
    for (int q = 0; q < 4; q++) {
        float rr = fmaxf(Arr * rv[q] + Ari * iv[q] + oR, 0.f);
        float ii = fmaxf(Air * rv[q] + Aii * iv[q] + oI, 0.f);
        float m = fmaf(rr, rr, ii * ii);
        if (m > bm) { bm = m; brv = rr; biv = ii; }
    }
    int k = (c * PH2 + ph) * PW2 + pw;
    P2Tr[k * BB + b] = brv;
    P2Ti[k * BB + b] = biv;
}

// ============================================================
// complex GEMM, partial-store variant (FC1). grid (8, FC1SPLIT).
// ============================================================
#define GKC 32
__global__ __launch_bounds__(256) void k_gemm_cplx_part(
                            const float* __restrict__ XTr, const float* __restrict__ XTi,
                            const float* __restrict__ Wr, const float* __restrict__ Wi,
                            float* __restrict__ partR, float* __restrict__ partI,
                            int K, int nStages, int nSplit) {
    __shared__ float lxr[GKC][64], lxi[GKC][64];
    __shared__ float lwr[GKC][68], lwi[GKC][68];
    int tid = threadIdx.x;
    int n0 = blockIdx.x * 64;
    int split = blockIdx.y;
    int bq = tid & 15, nq = tid >> 4;
    int nl = tid & 63, kg = tid >> 6;
    float accR[4][4] = {}, accI[4][4] = {};
    for (int st = split; st < nStages; st += nSplit) {
        int k0 = st * GKC;
        __syncthreads();
#pragma unroll
        for (int u = 0; u < 2; u++) {
            int p = u * 1024 + tid * 4;
            int g = k0 * 64 + p;
            float4 vr = make_float4(0.f, 0.f, 0.f, 0.f), vi = vr;
            if (g < K * 64) {
                vr = *(const float4*)(XTr + g);
                vi = *(const float4*)(XTi + g);
            }
            *(float4*)&((float*)lxr)[p] = vr;
            *(float4*)&((float*)lxi)[p] = vi;
        }
#pragma unroll
        for (int u = 0; u < 2; u++) {
            int koff = kg * 8 + u * 4;
            int k = k0 + koff;
            float4 vr = make_float4(0.f, 0.f, 0.f, 0.f), vi = vr;
            if (k < K) {
                vr = *(const float4*)(Wr + (size_t)(n0 + nl) * K + k);
                vi = *(const float4*)(Wi + (size_t)(n0 + nl) * K + k);
            }
            lwr[koff + 0][nl] = vr.x; lwr[koff + 1][nl] = vr.y;
            lwr[koff + 2][nl] = vr.z; lwr[koff + 3][nl] = vr.w;
            lwi[koff + 0][nl] = vi.x; lwi[koff + 1][nl] = vi.y;
            lwi[koff + 2][nl] = vi.z; lwi[koff + 3][nl] = vi.w;
        }
        __syncthreads();
#pragma unroll 4
        for (int kk = 0; kk < GKC; kk++) {
            float4 xr4 = *(const float4*)&lxr[kk][bq * 4];
            float4 xi4 = *(const float4*)&lxi[kk][bq * 4];
            float4 wr4 = *(const float4*)&lwr[kk][nq * 4];
            float4 wi4 = *(const float4*)&lwi[kk][nq * 4];
            float xra[4] = {xr4.x, xr4.y, xr4.z, xr4.w};
            float xia[4] = {xi4.x, xi4.y, xi4.z, xi4.w};
            float wra[4] = {wr4.x, wr4.y, wr4.z, wr4.w};
            float wia[4] = {wi4.x, wi4.y, wi4.z, wi4.w};
#pragma unroll
            for (int i = 0; i < 4; i++)
#pragma unroll
                for (int j = 0; j < 4; j++) {
                    CMAC(accR[i][j], accI[i][j], xra[i], xia[i], wra[j], wia[j]);
                }
        }
    }
    float* bR = partR + ((size_t)(split * 8 + blockIdx.x) << 12);
    float* bI = partI + ((size_t)(split * 8 + blockIdx.x) << 12);
#pragma unroll
    for (int i = 0; i < 4; i++) {
        int row = (bq * 4 + i) * 64 + nq * 4;
        *(float4*)&bR[row] = make_float4(accR[i][0], accR[i][1], accR[i][2], accR[i][3]);
        *(float4*)&bI[row] = make_float4(accI[i][0], accI[i][1], accI[i][2], accI[i][3]);
    }
}

// ============================================================
// FC1 partial reduce: fc1[b][n] = bias[n] + sum_s part
// ============================================================
__global__ __launch_bounds__(256) void k_fc1_reduce(
                            const float* __restrict__ partR, const float* __restrict__ partI,
                            const float* __restrict__ f1br, const float* __restrict__ f1bi,
                            float* __restrict__ fc1r, float* __restrict__ fc1i) {
    int idx = blockIdx.x * 256 + threadIdx.x;     // [b][n], n fastest
    int b = idx >> 9, n = idx & 511;
    int nb = n >> 6, nl = n & 63;
    size_t off = ((size_t)nb << 12) + b * 64 + nl;
    float r = f1br[n], i = f1bi[n];
    for (int s = 0; s < FC1SPLIT; s++) {
        r += partR[off + ((size_t)s << 15)];      // s*8*4096
        i += partI[off + ((size_t)s << 15)];
    }
    fc1r[idx] = r;
    fc1i[idx] = i;
}

// ============================================================
// complex GEMM, atomic variant (FC2 — small, low contention)
// ============================================================
__global__ __launch_bounds__(256) void k_gemm_cplx(
                            const float* __restrict__ XTr, const float* __restrict__ XTi,
                            const float* __restrict__ Wr, const float* __restrict__ Wi,
                            float* __restrict__ outR, float* __restrict__ outI,
                            int K, int nStages, int nSplit) {
    __shared__ float lxr[GKC][64], lxi[GKC][64];
    __shared__ float lwr[GKC][68], lwi[GKC][68];
    int tid = threadIdx.x;
    int n0 = blockIdx.x * 64;
    int split = blockIdx.y;
    int bq = tid & 15, nq = tid >> 4;
    int nl = tid & 63, kg = tid >> 6;
    float accR[4][4] = {}, accI[4][4] = {};
    for (int st = split; st < nStages; st += nSplit) {
        int k0 = st * GKC;
        __syncthreads();
#pragma unroll
        for (int u = 0; u < 2; u++) {
            int p = u * 1024 + tid * 4;
            int g = k0 * 64 + p;
            float4 vr = make_float4(0.f, 0.f, 0.f, 0.f), vi = vr;
            if (g < K * 64) {
                vr = *(const float4*)(XTr + g);
                vi = *(const float4*)(XTi + g);
            }
            *(float4*)&((float*)lxr)[p] = vr;
            *(float4*)&((float*)lxi)[p] = vi;
        }
#pragma unroll
        for (int u = 0; u < 2; u++) {
            int koff = kg * 8 + u * 4;
            int k = k0 + koff;
            float4 vr = make_float4(0.f, 0.f, 0.f, 0.f), vi = vr;
            if (k < K) {
                vr = *(const float4*)(Wr + (size_t)(n0 + nl) * K + k);
                vi = *(const float4*)(Wi + (size_t)(n0 + nl) * K + k);
            }
            lwr[koff + 0][nl] = vr.x; lwr[koff + 1][nl] = vr.y;
            lwr[koff + 2][nl] = vr.z; lwr[koff + 3][nl] = vr.w;
            lwi[koff + 0][nl] = vi.x; lwi[koff + 1][nl] = vi.y;
            lwi[koff + 2][nl] = vi.z; lwi[koff + 3][nl] = vi.w;
        }
        __syncthreads();
#pragma unroll 4
        for (int kk = 0; kk < GKC; kk++) {
            float4 xr4 = *(const float4*)&lxr[kk][bq * 4];
            float4 xi4 = *(const float4*)&lxi[kk][bq * 4];
            float4 wr4 = *(const float4*)&lwr[kk][nq * 4];
            float4 wi4 = *(const float4*)&lwi[kk][nq * 4];
            float xra[4] = {xr4.x, xr4.y, xr4.z, xr4.w};
            float xia[4] = {xi4.x, xi4.y, xi4.z, xi4.w};
            float wra[4] = {wr4.x, wr4.y, wr4.z, wr4.w};
            float wia[4] = {wi4.x, wi4.y, wi4.z, wi4.w};
#pragma unroll
            for (int i = 0; i < 4; i++)
#pragma unroll
                for (int j = 0; j < 4; j++) {
                    CMAC(accR[i][j], accI[i][j], xra[i], xia[i], wra[j], wia[j]);
                }
        }
    }
#pragma unroll
    for (int i = 0; i < 4; i++)
#pragma unroll
        for (int j = 0; j < 4; j++) {
            int b = bq * 4 + i;
            int n = n0 + nq * 4 + j;
            unsafeAtomicAdd(&outR[b * HID + n], accR[i][j]);
            unsafeAtomicAdd(&outI[b * HID + n], accI[i][j]);
        }
}

// ============================================================
// FC BN coef (batch axis only, N=64), C features
// ============================================================
__global__ __launch_bounds__(256) void k_bnfc_coef(
                            const float* __restrict__ inr, const float* __restrict__ ini, int C,
                            const float* __restrict__ grr, const float* __restrict__ gri,
                            const float* __restrict__ gii,
                            const float* __restrict__ ber, const float* __restrict__ bei,
                            float* __restrict__ coef) {
    int f = blockIdx.x * 256 + threadIdx.x;
    if (f >= C) return;
    double sr = 0, si = 0, srr = 0, sii = 0, sri = 0;
    for (int b = 0; b < BB; b++) {
        double r = inr[b * C + f], i = ini[b * C + f];
        sr += r; si += i; srr += r * r; sii += i * i; sri += r * i;
    }
    double invN = 1.0 / BB;
    double mr = sr * invN, mi = si * invN;
    double Vrr = srr * invN - mr * mr + EPSV;
    double Vii = sii * invN - mi * mi + EPSV;
    double Vri = sri * invN - mr * mi;
    double s = sqrt(Vrr * Vii - Vri * Vri);
    double t = sqrt(Vrr + Vii + 2.0 * s);
    double inv = 1.0 / (s * t);
    double Rrr = (Vii + s) * inv, Rii = (Vrr + s) * inv, Rri = -Vri * inv;
    double Grr = grr[f], Gri = gri[f], Gii = gii[f];
    double Arr = Grr * Rrr + Gri * Rri, Ari = Grr * Rri + Gri * Rii;
    double Air = Gri * Rrr + Gii * Rri, Aii = Gri * Rri + Gii * Rii;
    coef[f * 6 + 0] = (float)Arr;
    coef[f * 6 + 1] = (float)Ari;
    coef[f * 6 + 2] = (float)Air;
    coef[f * 6 + 3] = (float)Aii;
    coef[f * 6 + 4] = (float)((double)ber[f] - (Arr * mr + Ari * mi));
    coef[f * 6 + 5] = (float)((double)bei[f] - (Air * mr + Aii * mi));
}

// ============================================================
// FC BN apply + relu; optional transposed output [f][64]
// ============================================================
__global__ __launch_bounds__(256) void k_bnfc_apply(
                             const float* __restrict__ inr, const float* __restrict__ ini,
                             const float* __restrict__ coef,
                             float* __restrict__ outr, float* __restrict__ outi,
                             int C, int transposeOut) {
    int idx = blockIdx.x * 256 + threadIdx.x;
    if (idx >= BB * C) return;
    int f = idx % C;
    int b = idx / C;
    float r = inr[idx], i = ini[idx];
    float rr = fmaxf(coef[f * 6 + 0] * r + coef[f * 6 + 1] * i + coef[f * 6 + 4], 0.f);
    float ii = fmaxf(coef[f * 6 + 2] * r + coef[f * 6 + 3] * i + coef[f * 6 + 5], 0.f);
    if (transposeOut) { outr[f * BB + b] = rr; outi[f * BB + b] = ii; }
    else              { outr[idx] = rr;        outi[idx] = ii; }
}

// ============================================================
// classifier (512->10 complex) + |z|^2 + log_softmax
// ============================================================
__global__ __launch_bounds__(64) void k_classifier(
                             const float* __restrict__ xr, const float* __restrict__ xi,
                             const float* __restrict__ cwr, const float* __restrict__ cwi,
                             const float* __restrict__ cbr, const float* __restrict__ cbi,
                             float* __restrict__ out) {
    int b = blockIdx.x;
    int lane = threadIdx.x;
    __shared__ float z[NCLS];
    for (int cls = 0; cls < NCLS; cls++) {
        float ar = 0.f, ai = 0.f;
#pragma unroll
        for (int j = 0; j < 8; j++) {
            int k = j * 64 + lane;
            float xrv = xr[b * HID + k], xiv = xi[b * HID + k];
            float wr = cwr[cls * HID + k], wi = cwi[cls * HID + k];
            CMAC(ar, ai, xrv, xiv, wr, wi);
        }
#pragma unroll
        for (int m = 32; m >= 1; m >>= 1) {
            ar += __shfl_xor(ar, m, 64);
            ai += __shfl_xor(ai, m, 64);
        }
        if (lane == 0) {
            float hr = ar + cbr[cls], hi = ai + cbi[cls];
            z[cls] = fmaf(hr, hr, hi * hi);
        }
    }
    __syncthreads();
    if (lane == 0) {
        float mx = z[0];
#pragma unroll
        for (int c = 1; c < NCLS; c++) mx = fmaxf(mx, z[c]);
        float s = 0.f;
#pragma unroll
        for (int c = 0; c < NCLS; c++) s += expf(z[c] - mx);
        float ls = logf(s);
#pragma unroll
        for (int c = 0; c < NCLS; c++) out[b * NCLS + c] = z[c] - mx - ls;
    }
}

// ============================================================
extern "C" void kernel_launch(void* const* d_in, const int* in_sizes, int n_in,
                              void* d_out, int out_size, void* d_ws, size_t ws_size,
                              hipStream_t stream) {
    const float* x_re = (const float*)d_in[0];
    const float* x_im = (const float*)d_in[1];
    const float* w1r = (const float*)d_in[2];
    const float* w1i = (const float*)d_in[3];
    const float* b1r = (const float*)d_in[4];
    const float* b1i = (const float*)d_in[5];
    const float* g1rr = (const float*)d_in[6];
    const float* g1ri = (const float*)d_in[7];
    const float* g1ii = (const float*)d_in[8];
    const float* be1r = (const float*)d_in[9];
    const float* be1i = (const float*)d_in[10];
    const float* w2r = (const float*)d_in[11];
    const float* w2i = (const float*)d_in[12];
    const float* b2r = (const float*)d_in[13];
    const float* b2i = (const float*)d_in[14];
    const float* g2rr = (const float*)d_in[15];
    const float* g2ri = (const float*)d_in[16];
    const float* g2ii = (const float*)d_in[17];
    const float* be2r = (const float*)d_in[18];
    const float* be2i = (const float*)d_in[19];
    const float* f1wr = (const float*)d_in[20];
    const float* f1wi = (const float*)d_in[21];
    const float* f1br = (const float*)d_in[22];
    const float* f1bi = (const float*)d_in[23];
    const float* g3rr = (const float*)d_in[24];
    const float* g3ri = (const float*)d_in[25];
    const float* g3ii = (const float*)d_in[26];
    const float* be3r = (const float*)d_in[27];
    const float* be3i = (const float*)d_in[28];
    const float* f2wr = (const float*)d_in[29];
    const float* f2wi = (const float*)d_in[30];
    const float* f2br = (const float*)d_in[31];
    const float* f2bi = (const float*)d_in[32];
    const float* g4rr = (const float*)d_in[33];
    const float* g4ri = (const float*)d_in[34];
    const float* g4ii = (const float*)d_in[35];
    const float* be4r = (const float*)d_in[36];
    const float* be4i = (const float*)d_in[37];
    const float* cwr = (const float*)d_in[38];
    const float* cwi = (const float*)d_in[39];
    const float* cbr = (const float*)d_in[40];
    const float* cbi = (const float*)d_in[41];
    float* out = (float*)d_out;

    char* ws = (char*)d_ws;
    size_t off = 0;
    auto alloc = [&](size_t nbytes) -> void* {
        off = (off + 255) & ~(size_t)255;
        void* p = ws + off;
        off += nbytes;
        return p;
    };
    float* P1r   = (float*)alloc((size_t)BB * C1c * PH1 * PW1 * 4);
    float* P1i   = (float*)alloc((size_t)BB * C1c * PH1 * PW1 * 4);
    float* buf2r = (float*)alloc((size_t)BB * C2c * OH2 * OW2 * 4);   // 26.6 MB
    float* buf2i = (float*)alloc((size_t)BB * C2c * OH2 * OW2 * 4);   // 26.6 MB
    float* P2Tr  = (float*)alloc((size_t)FLAT * BB * 4);
    float* P2Ti  = (float*)alloc((size_t)FLAT * BB * 4);
    float* fc1r  = (float*)alloc((size_t)BB * HID * 4);
    float* fc1i  = (float*)alloc((size_t)BB * HID * 4);
    float* fc1aTr = (float*)alloc((size_t)HID * BB * 4);
    float* fc1aTi = (float*)alloc((size_t)HID * BB * 4);
    float* fc2r  = (float*)alloc((size_t)BB * HID * 4);
    float* fc2i  = (float*)alloc((size_t)BB * HID * 4);
    float* fc2ar = (float*)alloc((size_t)BB * HID * 4);
    float* fc2ai = (float*)alloc((size_t)BB * HID * 4);
    double* part1 = (double*)alloc((size_t)C1c * 5 * NB1 * 8);
    double* part2 = (double*)alloc((size_t)C2c * 5 * NB2 * 8);
    double* sums1 = (double*)alloc(C1c * 5 * 8);
    double* sums2 = (double*)alloc(C2c * 5 * 8);
    float* coef1 = (float*)alloc(C1c * 6 * 4);
    float* coef2 = (float*)alloc(C2c * 6 * 4);
    float* coefF1 = (float*)alloc(HID * 6 * 4);
    float* coefF2 = (float*)alloc(HID * 6 * 4);
    // FC1 partials alias buf2 (dead after k_bn2_pool)
    float* gpR = buf2r;
    float* gpI = buf2i;

    // 0) init (fc2 bias only; fc1 bias folded into k_fc1_reduce)
    k_init<<<128, 256, 0, stream>>>(fc2r, fc2i, f2br, f2bi);
    // 1) conv1 stats partials (8-wide)
    k_conv1_stats<<<dim3(NB1, C1c), 256, 0, stream>>>(x_re, x_im, w1r, w1i, b1r, b1i, part1);
    k_part_reduce<<<C1c, 320, 0, stream>>>(part1, NB1, sums1);
    // 2) BN1 coefs
    k_bn_coef<<<1, 64, 0, stream>>>(sums1, C1c, 1.0 / ((double)BB * OH1 * OW1),
                                    g1rr, g1ri, g1ii, be1r, be1i, coef1);
    // 3) conv1 + BN + relu + pool -> P1
    k_conv1_apply_pool<<<dim3(728, C1c), 256, 0, stream>>>(x_re, x_im, w1r, w1i, b1r, b1i,
                                                           coef1, P1r, P1i);
    // 4) conv2 + store + stats partials (round-5 config, grid (325,10))
    k_conv2_stats<<<dim3(NB2, C2c / COG), 256, 0, stream>>>(P1r, P1i, w2r, w2i, b2r, b2i,
                                                            buf2r, buf2i, part2);
    k_part_reduce<<<C2c, 320, 0, stream>>>(part2, NB2, sums2);
    // 5) BN2 coefs
    k_bn_coef<<<1, 64, 0, stream>>>(sums2, C2c, 1.0 / ((double)BB * OH2 * OW2),
                                    g2rr, g2ri, g2ii, be2r, be2i, coef2);
    // 6) BN2 + relu + pool -> P2T [26000][64]  (last reader of buf2)
    k_bn2_pool<<<6500, 256, 0, stream>>>(buf2r, buf2i, coef2, P2Tr, P2Ti);
    // 7) FC1 GEMM: split-K 128, partial tiles into gp (aliases buf2), then reduce
    k_gemm_cplx_part<<<dim3(8, FC1SPLIT), 256, 0, stream>>>(P2Tr, P2Ti, f1wr, f1wi,
                                                            gpR, gpI, FLAT, 813, FC1SPLIT);
    k_fc1_reduce<<<128, 256, 0, stream>>>(gpR, gpI, f1br, f1bi, fc1r, fc1i);
    // 8) BN3 coefs
    k_bnfc_coef<<<2, 256, 0, stream>>>(fc1r, fc1i, HID, g3rr, g3ri, g3ii, be3r, be3i, coefF1);
    // 9) BN3 apply + relu -> transposed [512][64]
    k_bnfc_apply<<<128, 256, 0, stream>>>(fc1r, fc1i, coefF1, fc1aTr, fc1aTi, HID, 1);
    // 10) FC2 GEMM (K=512, 16 stages, split 16, atomic variant)
    k_gemm_cplx<<<dim3(8, 16), 256, 0, stream>>>(fc1aTr, fc1aTi, f2wr, f2wi, fc2r, fc2i,
                                                 HID, 16, 16);
    // 11) BN4 coefs
    k_bnfc_coef<<<2, 256, 0, stream>>>(fc2r, fc2i, HID, g4rr, g4ri, g4ii, be4r, be4i, coefF2);
    // 12) BN4 apply + relu -> [64][512]
    k_bnfc_apply<<<128, 256, 0, stream>>>(fc2r, fc2i, coefF2, fc2ar, fc2ai, HID, 0);
    // 13) classifier + log_softmax
    k_classifier<<<64, 64, 0, stream>>>(fc2ar, fc2ai, cwr, cwi, cbr, cbi, out);
}